// Round 8
// baseline (923.630 us; speedup 1.0000x reference)
//
#include <hip/hip_runtime.h>
#include <math.h>

// B=32, C=2048, N=288(==PATCH), Q=16, proto tokens=2048
static constexpr float SCALE = 0.022097086912079612f; // 2048^-0.5

typedef __bf16 bf16x2 __attribute__((ext_vector_type(2)));
typedef __bf16 bf16x4 __attribute__((ext_vector_type(4)));
typedef __bf16 bf16x8 __attribute__((ext_vector_type(8)));
typedef float  f32x2  __attribute__((ext_vector_type(2)));
typedef float  f32x4  __attribute__((ext_vector_type(4)));

// ---------------- reduction helpers ----------------
__device__ __forceinline__ float wred_sum(float v){
  #pragma unroll
  for (int o=32;o>0;o>>=1) v += __shfl_down(v,o,64);
  return v;
}
__device__ __forceinline__ float wred_max(float v){
  #pragma unroll
  for (int o=32;o>0;o>>=1) v = fmaxf(v, __shfl_down(v,o,64));
  return v;
}
__device__ __forceinline__ float block_sum(float v, float* red){
  int tid=threadIdx.x, w=tid>>6, l=tid&63, nw=(int)(blockDim.x>>6);
  v = wred_sum(v);
  __syncthreads();
  if (l==0) red[w]=v;
  __syncthreads();
  float r=0.f;
  for (int i=0;i<nw;i++) r += red[i];
  return r;
}
__device__ __forceinline__ float block_max(float v, float* red){
  int tid=threadIdx.x, w=tid>>6, l=tid&63, nw=(int)(blockDim.x>>6);
  v = wred_max(v);
  __syncthreads();
  if (l==0) red[w]=v;
  __syncthreads();
  float r=red[0];
  for (int i=1;i<nw;i++) r = fmaxf(r, red[i]);
  return r;
}

// ---------------- MFMA split-bf16 NT GEMM (fp32 inputs), Part split-K ----------------
template<int MT, int NT, int WM, int WN>
__global__ __launch_bounds__(256, 2)
void gemm_nt_mfma(float* __restrict__ Cm, const float* __restrict__ Am,
                  const float* __restrict__ Bm, int M, int N, int K,
                  int lda, int ldb, int ldc, long sA, long sB, long sC,
                  float alpha, int KS, float* __restrict__ Part)
{
  constexpr int BM = MT*16*WM;
  constexpr int BN = NT*16*WN;
  constexpr int LDH = 40;
  constexpr int AST = (BM+31)/32;
  constexpr int BST = (BN+31)/32;
  __shared__ __bf16 Ah[BM*LDH];
  __shared__ __bf16 Al[BM*LDH];
  __shared__ __bf16 Bh[BN*LDH];
  __shared__ __bf16 Bl[BN*LDH];
  int ZZ = gridDim.z / KS;
  int z  = blockIdx.z % ZZ;
  int ks = blockIdx.z / ZZ;
  const float* A = Am + (long)z*sA;
  const float* B = Bm + (long)z*sB;
  float* C = Cm + (long)z*sC;
  int Kc = ((K + KS*32 - 1) / (KS*32)) * 32;
  int kbeg = ks*Kc;
  int kend = min(K, kbeg + Kc);
  int m0 = blockIdx.y*BM, n0 = blockIdx.x*BN;
  int t = threadIdx.x;
  int srow = t>>3, skoff = (t&7)*4;

  float4 areg[AST], breg[BST];
  auto loadAB = [&](int k0){
    #pragma unroll
    for (int s=0;s<AST;++s){
      int row = srow + 32*s; int gm = m0+row;
      areg[s] = make_float4(0.f,0.f,0.f,0.f);
      if (row < BM && gm < M) areg[s] = *(const float4*)(A + (long)gm*lda + k0 + skoff);
    }
    #pragma unroll
    for (int s=0;s<BST;++s){
      int row = srow + 32*s; int gn = n0+row;
      breg[s] = make_float4(0.f,0.f,0.f,0.f);
      if (row < BN && gn < N) breg[s] = *(const float4*)(B + (long)gn*ldb + k0 + skoff);
    }
  };
  auto writeLDS = [&](){
    #pragma unroll
    for (int s=0;s<AST;++s){
      int row = srow + 32*s;
      if (row < BM){
        float vv[4] = {areg[s].x, areg[s].y, areg[s].z, areg[s].w};
        bf16x4 hv, lv;
        #pragma unroll
        for (int e=0;e<4;++e){
          __bf16 h = (__bf16)vv[e];
          hv[e] = h;
          lv[e] = (__bf16)(vv[e] - (float)h);
        }
        *(bf16x4*)&Ah[row*LDH + skoff] = hv;
        *(bf16x4*)&Al[row*LDH + skoff] = lv;
      }
    }
    #pragma unroll
    for (int s=0;s<BST;++s){
      int row = srow + 32*s;
      if (row < BN){
        float vv[4] = {breg[s].x, breg[s].y, breg[s].z, breg[s].w};
        bf16x4 hv, lv;
        #pragma unroll
        for (int e=0;e<4;++e){
          __bf16 h = (__bf16)vv[e];
          hv[e] = h;
          lv[e] = (__bf16)(vv[e] - (float)h);
        }
        *(bf16x4*)&Bh[row*LDH + skoff] = hv;
        *(bf16x4*)&Bl[row*LDH + skoff] = lv;
      }
    }
  };

  int lane = t & 63, wid = t >> 6;
  int wm = (WM==1) ? 0 : (wid / WN);
  int wn = wid % WN;
  int mw = wm*MT*16, nw = wn*NT*16;
  int fr = lane & 15, fq = (lane>>4)*8;

  f32x4 acc[MT][NT];
  #pragma unroll
  for (int i=0;i<MT;++i)
    #pragma unroll
    for (int j=0;j<NT;++j) acc[i][j] = (f32x4){0.f,0.f,0.f,0.f};

  if (kbeg < kend) loadAB(kbeg);
  for (int k0=kbeg; k0<kend; k0+=32){
    writeLDS();
    __syncthreads();
    if (k0+32 < kend) loadAB(k0+32);
    bf16x8 ah[MT], al[MT], bh[NT], bl[NT];
    #pragma unroll
    for (int i=0;i<MT;++i){
      ah[i] = *(const bf16x8*)&Ah[(mw+i*16+fr)*LDH + fq];
      al[i] = *(const bf16x8*)&Al[(mw+i*16+fr)*LDH + fq];
    }
    #pragma unroll
    for (int j=0;j<NT;++j){
      bh[j] = *(const bf16x8*)&Bh[(nw+j*16+fr)*LDH + fq];
      bl[j] = *(const bf16x8*)&Bl[(nw+j*16+fr)*LDH + fq];
    }
    #pragma unroll
    for (int i=0;i<MT;++i)
      #pragma unroll
      for (int j=0;j<NT;++j){
        acc[i][j] = __builtin_amdgcn_mfma_f32_16x16x32_bf16(ah[i], bh[j], acc[i][j], 0,0,0);
        acc[i][j] = __builtin_amdgcn_mfma_f32_16x16x32_bf16(ah[i], bl[j], acc[i][j], 0,0,0);
        acc[i][j] = __builtin_amdgcn_mfma_f32_16x16x32_bf16(al[i], bh[j], acc[i][j], 0,0,0);
      }
    __syncthreads();
  }
  float wf = (KS==1) ? alpha : 1.f;
  float* Cw = C; int ldw = ldc;
  if (ks > 0){ Cw = Part + ((long)(ks-1)*ZZ + z)*(long)M*N; ldw = N; }
  int er = (lane>>4)*4, ec = lane & 15;
  #pragma unroll
  for (int i=0;i<MT;++i){
    int mbase = m0 + mw + i*16 + er;
    #pragma unroll
    for (int r=0;r<4;++r){
      int mm = mbase + r;
      if (mm < M){
        long cro = (long)mm*ldw;
        #pragma unroll
        for (int j=0;j<NT;++j){
          int nn = n0 + nw + j*16 + ec;
          if (nn < N) Cw[cro + nn] = wf*acc[i][j][r];
        }
      }
    }
  }
}

// ---------------- MFMA NT GEMM on pre-split bf16 hi/lo planes (batched + gather) ----------------
// Flat 1D grid with chunked XCD swizzle: blocks sharing an A-panel (same y,z)
// get consecutive in-XCD slots so each XCD's L2 fetches shared panels once.
template<int MT, int NT, int WM, int WN>
__global__ __launch_bounds__(256, 4)
void gemm_nt_bsg(float* __restrict__ Cm,
                 const __bf16* __restrict__ Ahg, const __bf16* __restrict__ Alg,
                 const __bf16* __restrict__ Bhg, const __bf16* __restrict__ Blg,
                 int M, int N, int K, int lda, int ldb, int ldc,
                 long sA, long sB, long sC,
                 float alpha, const int* __restrict__ browidx, long sBrow,
                 int SX, int SY, int SZ, int KS, float* __restrict__ Part)
{
  constexpr int BM = MT*16*WM;
  constexpr int BN = NT*16*WN;
  constexpr int LDH = 40;
  __shared__ __bf16 Ah[BM*LDH];
  __shared__ __bf16 Al[BM*LDH];
  __shared__ __bf16 Bh[BN*LDH];
  __shared__ __bf16 Bl[BN*LDH];
  int total = SX*SY*SZ;
  int bid = blockIdx.x;
  int w = (bid & 7)*(total >> 3) + (bid >> 3);   // chunked XCD transform (total%8==0)
  int bx = w % SX; int g = w / SX;
  int by = g % SY; int bz = g / SY;
  int ZZ = SZ / KS;
  int z  = bz % ZZ;
  int ks = bz / ZZ;
  const __bf16* Ahb = Ahg + (long)z*sA;
  const __bf16* Alb = Alg + (long)z*sA;
  const __bf16* Bhb = Bhg + (long)z*sB;
  const __bf16* Blb = Blg + (long)z*sB;
  float* C = Cm + (long)z*sC;
  const bool useB = (browidx != nullptr);
  const int* brow = useB ? (browidx + (long)z*sBrow) : nullptr;
  int Kc = ((K + KS*32 - 1) / (KS*32)) * 32;
  int kbeg = ks*Kc;
  int kend = min(K, kbeg + Kc);
  int m0 = by*BM, n0 = bx*BN;
  int t = threadIdx.x;
  constexpr int ASl = (BM*4 + 255)/256;
  constexpr int BSl = (BN*4 + 255)/256;
  bf16x8 arh[ASl], arl[ASl], brh[BSl], brl[BSl];
  bf16x8 zed;
  #pragma unroll
  for (int e=0;e<8;++e) zed[e] = (__bf16)0.f;

  auto loadAB = [&](int k0){
    #pragma unroll
    for (int i=0;i<ASl;++i){
      int s = t + 256*i;
      arh[i] = zed; arl[i] = zed;
      if (s < BM*4){
        int row = s>>2, koff = (s&3)*8; int gm = m0+row;
        if (gm < M){
          long off = (long)gm*lda + k0 + koff;
          arh[i] = *(const bf16x8*)(Ahb + off);
          arl[i] = *(const bf16x8*)(Alb + off);
        }
      }
    }
    #pragma unroll
    for (int i=0;i<BSl;++i){
      int s = t + 256*i;
      brh[i] = zed; brl[i] = zed;
      if (s < BN*4){
        int row = s>>2, koff = (s&3)*8; int gn = n0+row;
        if (gn < N){
          long r = useB ? (long)brow[gn] : (long)gn;
          long off = r*ldb + k0 + koff;
          brh[i] = *(const bf16x8*)(Bhb + off);
          brl[i] = *(const bf16x8*)(Blb + off);
        }
      }
    }
  };
  auto writeLDS = [&](){
    #pragma unroll
    for (int i=0;i<ASl;++i){
      int s = t + 256*i;
      if (s < BM*4){
        int row = s>>2, koff = (s&3)*8;
        *(bf16x8*)&Ah[row*LDH + koff] = arh[i];
        *(bf16x8*)&Al[row*LDH + koff] = arl[i];
      }
    }
    #pragma unroll
    for (int i=0;i<BSl;++i){
      int s = t + 256*i;
      if (s < BN*4){
        int row = s>>2, koff = (s&3)*8;
        *(bf16x8*)&Bh[row*LDH + koff] = brh[i];
        *(bf16x8*)&Bl[row*LDH + koff] = brl[i];
      }
    }
  };

  int lane = t & 63, wid = t >> 6;
  int wm = (WM==1) ? 0 : (wid / WN);
  int wn = wid % WN;
  int mw = wm*MT*16, nw = wn*NT*16;
  int fr = lane & 15, fq = (lane>>4)*8;

  f32x4 acc[MT][NT];
  #pragma unroll
  for (int i=0;i<MT;++i)
    #pragma unroll
    for (int j=0;j<NT;++j) acc[i][j] = (f32x4){0.f,0.f,0.f,0.f};

  if (kbeg < kend) loadAB(kbeg);
  for (int k0=kbeg; k0<kend; k0+=32){
    writeLDS();
    __syncthreads();
    if (k0+32 < kend) loadAB(k0+32);
    bf16x8 ah[MT], al[MT], bh[NT], bl[NT];
    #pragma unroll
    for (int i=0;i<MT;++i){
      ah[i] = *(const bf16x8*)&Ah[(mw+i*16+fr)*LDH + fq];
      al[i] = *(const bf16x8*)&Al[(mw+i*16+fr)*LDH + fq];
    }
    #pragma unroll
    for (int j=0;j<NT;++j){
      bh[j] = *(const bf16x8*)&Bh[(nw+j*16+fr)*LDH + fq];
      bl[j] = *(const bf16x8*)&Bl[(nw+j*16+fr)*LDH + fq];
    }
    #pragma unroll
    for (int i=0;i<MT;++i)
      #pragma unroll
      for (int j=0;j<NT;++j){
        acc[i][j] = __builtin_amdgcn_mfma_f32_16x16x32_bf16(ah[i], bh[j], acc[i][j], 0,0,0);
        acc[i][j] = __builtin_amdgcn_mfma_f32_16x16x32_bf16(ah[i], bl[j], acc[i][j], 0,0,0);
        acc[i][j] = __builtin_amdgcn_mfma_f32_16x16x32_bf16(al[i], bh[j], acc[i][j], 0,0,0);
      }
    __syncthreads();
  }
  float wf = (KS==1) ? alpha : 1.f;
  float* Cw = C; int ldw = ldc;
  if (ks > 0){ Cw = Part + ((long)(ks-1)*ZZ + z)*(long)M*N; ldw = N; }
  int er = (lane>>4)*4, ec = lane & 15;
  #pragma unroll
  for (int i=0;i<MT;++i){
    int mbase = m0 + mw + i*16 + er;
    #pragma unroll
    for (int r=0;r<4;++r){
      int mm = mbase + r;
      if (mm < M){
        long cro = (long)mm*ldw;
        #pragma unroll
        for (int j=0;j<NT;++j){
          int nn = n0 + nw + j*16 + ec;
          if (nn < N) Cw[cro + nn] = wf*acc[i][j][r];
        }
      }
    }
  }
}

// ---------------- GMIX GEMM: A = S planes, B = x fp32 (convert), C = planes out ----------------
// Conceptual grid 16x3x32, flat-launched with chunked XCD swizzle.
__global__ __launch_bounds__(256, 4)
void gemm_gmix(const __bf16* __restrict__ Sh, const __bf16* __restrict__ Sl,
               const float* __restrict__ xg,
               __bf16* __restrict__ Gh, __bf16* __restrict__ Gl)
{
  constexpr int BM = 96, BN = 128, LDH = 40;
  __shared__ __bf16 Ah[BM*LDH];
  __shared__ __bf16 Al[BM*LDH];
  __shared__ __bf16 Bh[BN*LDH];
  __shared__ __bf16 Bl[BN*LDH];
  int bid = blockIdx.x;
  int w = (bid & 7)*192 + (bid >> 3);   // total 1536
  int bx = w % 16; int g = w / 16;
  int by = g % 3;  int z = g / 3;
  const __bf16* Azh = Sh + (long)z*82944;
  const __bf16* Azl = Sl + (long)z*82944;
  const float*  B   = xg + (long)z*589824;
  int m0 = by*BM, n0 = bx*BN;
  int t = threadIdx.x;
  int srow = t>>3, skoff = (t&7)*4;
  bf16x8 arh[2], arl[2];
  float4 breg[4];
  auto loadAB = [&](int k0){
    #pragma unroll
    for (int i=0;i<2;++i){
      int s = t + 256*i;
      if (s < 384){
        int row = s>>2, koff = (s&3)*8;
        long off = (long)(m0+row)*288 + k0 + koff;
        arh[i] = *(const bf16x8*)(Azh + off);
        arl[i] = *(const bf16x8*)(Azl + off);
      }
    }
    #pragma unroll
    for (int si=0;si<4;++si){
      int row = srow + 32*si;
      breg[si] = *(const float4*)(B + (long)(n0+row)*288 + k0 + skoff);
    }
  };
  auto writeLDS = [&](){
    #pragma unroll
    for (int i=0;i<2;++i){
      int s = t + 256*i;
      if (s < 384){
        int row = s>>2, koff = (s&3)*8;
        *(bf16x8*)&Ah[row*LDH + koff] = arh[i];
        *(bf16x8*)&Al[row*LDH + koff] = arl[i];
      }
    }
    #pragma unroll
    for (int si=0;si<4;++si){
      int row = srow + 32*si;
      float vv[4] = {breg[si].x, breg[si].y, breg[si].z, breg[si].w};
      bf16x4 hv, lv;
      #pragma unroll
      for (int e=0;e<4;++e){
        __bf16 h = (__bf16)vv[e];
        hv[e] = h;
        lv[e] = (__bf16)(vv[e] - (float)h);
      }
      *(bf16x4*)&Bh[row*LDH + skoff] = hv;
      *(bf16x4*)&Bl[row*LDH + skoff] = lv;
    }
  };
  int lane = t & 63, wid = t >> 6;
  int wm = wid >> 1, wn = wid & 1;
  int mw = wm*48, nw = wn*64;
  int fr = lane & 15, fq = (lane>>4)*8;
  f32x4 acc[3][4];
  #pragma unroll
  for (int i=0;i<3;++i)
    #pragma unroll
    for (int j=0;j<4;++j) acc[i][j] = (f32x4){0.f,0.f,0.f,0.f};

  loadAB(0);
  for (int k0=0; k0<288; k0+=32){
    writeLDS();
    __syncthreads();
    if (k0+32 < 288) loadAB(k0+32);
    bf16x8 ah[3], al[3], bh[4], bl[4];
    #pragma unroll
    for (int i=0;i<3;++i){
      ah[i] = *(const bf16x8*)&Ah[(mw+i*16+fr)*LDH + fq];
      al[i] = *(const bf16x8*)&Al[(mw+i*16+fr)*LDH + fq];
    }
    #pragma unroll
    for (int j=0;j<4;++j){
      bh[j] = *(const bf16x8*)&Bh[(nw+j*16+fr)*LDH + fq];
      bl[j] = *(const bf16x8*)&Bl[(nw+j*16+fr)*LDH + fq];
    }
    #pragma unroll
    for (int i=0;i<3;++i)
      #pragma unroll
      for (int j=0;j<4;++j){
        acc[i][j] = __builtin_amdgcn_mfma_f32_16x16x32_bf16(ah[i], bh[j], acc[i][j], 0,0,0);
        acc[i][j] = __builtin_amdgcn_mfma_f32_16x16x32_bf16(ah[i], bl[j], acc[i][j], 0,0,0);
        acc[i][j] = __builtin_amdgcn_mfma_f32_16x16x32_bf16(al[i], bh[j], acc[i][j], 0,0,0);
      }
    __syncthreads();
  }
  int er = (lane>>4)*4, ec = lane & 15;
  #pragma unroll
  for (int i=0;i<3;++i){
    int mbase = m0 + mw + i*16 + er;
    #pragma unroll
    for (int r=0;r<4;++r){
      int mm = mbase + r;
      long ro = (long)z*589824 + (long)mm*2048;
      #pragma unroll
      for (int j=0;j<4;++j){
        int nn = n0 + nw + j*16 + ec;
        float v = acc[i][j][r];
        __bf16 h = (__bf16)v;
        Gh[ro + nn] = h;
        Gl[ro + nn] = (__bf16)(v - (float)h);
      }
    }
  }
}

// C[i] = alpha * (C[i] + sum parts), float4
__global__ __launch_bounds__(256) void k_reduce4(float* __restrict__ C, const float* __restrict__ Part,
                                                 long total, int S, float alpha){
  long n4 = total >> 2;
  for (long i = (long)blockIdx.x*blockDim.x + threadIdx.x; i < n4;
       i += (long)gridDim.x*blockDim.x){
    float4 v = ((float4*)C)[i];
    for (int s=0;s<S;++s){
      float4 p = ((const float4*)(Part + (long)s*total))[i];
      v.x += p.x; v.y += p.y; v.z += p.z; v.w += p.w;
    }
    v.x *= alpha; v.y *= alpha; v.z *= alpha; v.w *= alpha;
    ((float4*)C)[i] = v;
  }
}

// reduce + emit bf16 hi/lo planes (vectorized by 4)
__global__ __launch_bounds__(256) void k_reduce_split(float* __restrict__ C, const float* __restrict__ Part,
                                                      long total, int S, float alpha,
                                                      __bf16* __restrict__ H, __bf16* __restrict__ L){
  long n4 = total >> 2;
  for (long i = (long)blockIdx.x*blockDim.x + threadIdx.x; i < n4;
       i += (long)gridDim.x*blockDim.x){
    float4 v = ((float4*)C)[i];
    for (int s=0;s<S;++s){
      float4 p = ((const float4*)(Part + (long)s*total))[i];
      v.x += p.x; v.y += p.y; v.z += p.z; v.w += p.w;
    }
    v.x *= alpha; v.y *= alpha; v.z *= alpha; v.w *= alpha;
    ((float4*)C)[i] = v;
    float vv[4] = {v.x, v.y, v.z, v.w};
    bf16x4 h, l;
    #pragma unroll
    for (int e=0;e<4;++e){
      __bf16 hh = (__bf16)vv[e];
      h[e] = hh;
      l[e] = (__bf16)(vv[e] - (float)hh);
    }
    ((bf16x4*)H)[i] = h;
    ((bf16x4*)L)[i] = l;
  }
}

// flat fp32 -> bf16 hi/lo planes
__global__ __launch_bounds__(256) void k_split(const float* __restrict__ X,
                                               __bf16* __restrict__ H, __bf16* __restrict__ L, long n){
  long n4 = n >> 2;
  for (long i = (long)blockIdx.x*blockDim.x + threadIdx.x; i < n4;
       i += (long)gridDim.x*blockDim.x){
    float4 v = ((const float4*)X)[i];
    float vv[4] = {v.x, v.y, v.z, v.w};
    bf16x4 h, l;
    #pragma unroll
    for (int e=0;e<4;++e){
      __bf16 hh = (__bf16)vv[e];
      h[e] = hh;
      l[e] = (__bf16)(vv[e] - (float)hh);
    }
    ((bf16x4*)H)[i] = h;
    ((bf16x4*)L)[i] = l;
  }
}

// ---------------- fused skinny PV: bf16 planes + prefetch ----------------
__global__ __launch_bounds__(256, 2) void k_pv2(
    float* __restrict__ C, float* __restrict__ Part,
    const float* __restrict__ Pm, long sP, int K, int Kc,
    const __bf16* __restrict__ Gh, const __bf16* __restrict__ Gl,
    long sG, const int* __restrict__ SB)
{
  extern __shared__ float Pl[];   // [16][Kc]
  int b = blockIdx.y, ks = blockIdx.z;
  int kbeg = ks * Kc;
  int kend = min(K, kbeg + Kc);
  int len = kend - kbeg;
  int c0 = blockIdx.x*512 + threadIdx.x*2;
  const float* Pb = Pm + (long)b*sP;
  for (int i = threadIdx.x; i < 16*len; i += 256){
    int q = i / len, kk = i - q*len;
    Pl[q*Kc + kk] = Pb[(long)q*K + kbeg + kk];
  }
  __syncthreads();
  f32x2 acc[16];
  #pragma unroll
  for (int q=0;q<16;++q) acc[q] = (f32x2){0.f,0.f};
  int kk = 0;
  while (kk < len){
    int kg = kbeg + kk;
    int seg = kg / 288;
    int row = kg - seg*288;
    int nrow = min(288 - row, len - kk);
    long base = (SB ? (long)SB[(b<<2)+seg]*sG : (long)b*sG) + (long)row*2048 + c0;
    const __bf16* gh = Gh + base;
    const __bf16* gl = Gl + base;
    bf16x2 h0,h1,h2,h3,l0,l1,l2,l3;
    h0 = *(const bf16x2*)(gh);       l0 = *(const bf16x2*)(gl);
    h1 = *(const bf16x2*)(gh+2048);  l1 = *(const bf16x2*)(gl+2048);
    h2 = *(const bf16x2*)(gh+4096);  l2 = *(const bf16x2*)(gl+4096);
    h3 = *(const bf16x2*)(gh+6144);  l3 = *(const bf16x2*)(gl+6144);
    gh += 8192; gl += 8192;
    for (int r = 0; r < nrow; r += 4, kk += 4){
      bf16x2 nh0=h0,nh1=h1,nh2=h2,nh3=h3,nl0=l0,nl1=l1,nl2=l2,nl3=l3;
      if (r + 4 < nrow){
        nh0 = *(const bf16x2*)(gh);       nl0 = *(const bf16x2*)(gl);
        nh1 = *(const bf16x2*)(gh+2048);  nl1 = *(const bf16x2*)(gl+2048);
        nh2 = *(const bf16x2*)(gh+4096);  nl2 = *(const bf16x2*)(gl+4096);
        nh3 = *(const bf16x2*)(gh+6144);  nl3 = *(const bf16x2*)(gl+6144);
        gh += 8192; gl += 8192;
      }
      f32x2 g0, g1, g2, g3;
      g0[0]=(float)h0[0]+(float)l0[0]; g0[1]=(float)h0[1]+(float)l0[1];
      g1[0]=(float)h1[0]+(float)l1[0]; g1[1]=(float)h1[1]+(float)l1[1];
      g2[0]=(float)h2[0]+(float)l2[0]; g2[1]=(float)h2[1]+(float)l2[1];
      g3[0]=(float)h3[0]+(float)l3[0]; g3[1]=(float)h3[1]+(float)l3[1];
      #pragma unroll
      for (int q=0;q<16;++q){
        f32x4 p = *(const f32x4*)&Pl[q*Kc + kk];
        acc[q] += p[0]*g0;
        acc[q] += p[1]*g1;
        acc[q] += p[2]*g2;
        acc[q] += p[3]*g3;
      }
      h0=nh0; h1=nh1; h2=nh2; h3=nh3;
      l0=nl0; l1=nl1; l2=nl2; l3=nl3;
    }
  }
  float* Cw = (ks==0) ? C : (Part + (long)(ks-1)*1048576);
  long obase = (long)b*32768 + c0;
  #pragma unroll
  for (int q=0;q<16;++q) *(f32x2*)&Cw[obase + (long)q*2048] = acc[q];
}

// ---------------- small kernels ----------------
// transpose x -> XS planes + per-patch sum-of-squares (atomic)
__global__ void k_trs(const float* __restrict__ in, __bf16* __restrict__ oh,
                      __bf16* __restrict__ ol, float* __restrict__ m2){
  __shared__ float tile[32][33];
  __shared__ float cred[8][33];
  int bz = blockIdx.z;
  long zo = (long)bz*589824;
  int r0 = blockIdx.y*32, c0 = blockIdx.x*32;
  int tx = threadIdx.x, ty = threadIdx.y;
  float ss = 0.f;
  #pragma unroll
  for (int j=0;j<32;j+=8){
    float v = in[zo + (long)(r0+ty+j)*288 + c0+tx];
    tile[ty+j][tx] = v;
    ss += v*v;
  }
  cred[ty][tx] = ss;
  __syncthreads();
  #pragma unroll
  for (int j=0;j<32;j+=8){
    float v = tile[tx][ty+j];
    __bf16 h = (__bf16)v;
    long idx = zo + (long)(c0+ty+j)*2048 + r0+tx;
    oh[idx] = h;
    ol[idx] = (__bf16)(v - (float)h);
  }
  if (ty==0){
    float s = cred[0][tx];
    #pragma unroll
    for (int k=1;k<8;++k) s += cred[k][tx];
    atomicAdd(&m2[bz*288 + c0+tx], s);
  }
}

// transpose + split into bf16 hi/lo planes
__global__ void k_tr_split(const float* __restrict__ in, __bf16* __restrict__ oh,
                           __bf16* __restrict__ ol, int R, int C){
  __shared__ float tile[32][33];
  int r0 = blockIdx.y*32, c0 = blockIdx.x*32;
  int tx = threadIdx.x, ty = threadIdx.y;
  #pragma unroll
  for (int j=0;j<32;j+=8)
    tile[ty+j][tx] = in[(long)(r0+ty+j)*C + c0+tx];
  __syncthreads();
  #pragma unroll
  for (int j=0;j<32;j+=8){
    float v = tile[tx][ty+j];
    __bf16 h = (__bf16)v;
    long idx = (long)(c0+ty+j)*R + r0+tx;
    oh[idx] = h;
    ol[idx] = (__bf16)(v - (float)h);
  }
}

// batched rowstats: r<2048 -> X1 row, else X2 row (cols=2048)
__global__ __launch_bounds__(256) void k_rowstats2(const float* __restrict__ X1, const float* __restrict__ X2,
                                                   float* __restrict__ mu1, float* __restrict__ m21,
                                                   float* __restrict__ mu2, float* __restrict__ m22){
  int r = blockIdx.x;
  const float* row; float* mu; float* m2; int idx;
  if (r < 2048){ idx = r; row = X1 + (long)idx*2048; mu = mu1; m2 = m21; }
  else { idx = r - 2048; row = X2 + (long)idx*2048; mu = mu2; m2 = m22; }
  float s=0.f, s2=0.f;
  for (int c = threadIdx.x*4; c < 2048; c += 1024){
    float4 v = *(const float4*)(row+c);
    s  += v.x+v.y+v.z+v.w;
    s2 += v.x*v.x+v.y*v.y+v.z*v.z+v.w*v.w;
  }
  __shared__ float red[8];
  s  = block_sum(s,  red);
  s2 = block_sum(s2, red);
  if (threadIdx.x==0){ mu[idx]=s*(1.f/2048.f); m2[idx]=s2; }
}

// gram softmax: folded Part slice, l2norm scaling, emits S planes
__global__ __launch_bounds__(256) void k_softmax_gram_s(const float* __restrict__ S, const float* __restrict__ Part,
                                                        const float* __restrict__ m2xs,
                                                        __bf16* __restrict__ Hh, __bf16* __restrict__ Hl){
  int r = blockIdx.x;
  int b = r / 288, p = r % 288;
  const float* row = S + (long)r * 288;
  const float* prow = Part + (long)b*82944 + (long)p*288;
  const float* m2 = m2xs + (long)b*288;
  float rp = 1.f / fmaxf(sqrtf(m2[p]), 1e-12f);
  int tid = threadIdx.x;
  __shared__ float red[8];
  float lv[2];
  #pragma unroll
  for (int i=0;i<2;++i){
    int q = tid + i*256;
    lv[i] = (q<288) ? (row[q]+prow[q])*rp/fmaxf(sqrtf(m2[q]),1e-12f) : -1e30f;
  }
  float mx = fmaxf(lv[0], lv[1]);
  mx = block_max(mx, red);
  float s = 0.f;
  #pragma unroll
  for (int i=0;i<2;++i){
    int q = tid + i*256;
    float e = (q<288) ? expf(lv[i]-mx) : 0.f;
    lv[i]=e; s+=e;
  }
  s = block_sum(s, red);
  float inv = 1.f/s;
  #pragma unroll
  for (int i=0;i<2;++i){
    int q = tid + i*256;
    if (q<288){
      float v = lv[i]*inv;
      __bf16 h = (__bf16)v;
      long idx = (long)r*288 + q;
      Hh[idx] = h;
      Hl[idx] = (__bf16)(v - (float)h);
    }
  }
}

// softmax over rows of X[32*16][288] with folded Part sum
__global__ __launch_bounds__(256) void k_softmax_plain_r(float* __restrict__ X,
                                                         const float* __restrict__ Part,
                                                         int S, float alpha){
  int r = blockIdx.x; int b = r>>4, qq = r&15;
  float* row = X + (long)r * 288;
  int tid = threadIdx.x;
  __shared__ float red[8];
  float lv[2];
  #pragma unroll
  for (int i=0;i<2;++i){
    int q = tid + i*256;
    if (q<288){
      float v = row[q];
      for (int s=0;s<S;++s) v += Part[((long)s*32 + b)*4608 + (long)qq*288 + q];
      lv[i] = v*alpha;
    } else lv[i] = -1e30f;
  }
  float mx = fmaxf(lv[0], lv[1]);
  mx = block_max(mx, red);
  float s = 0.f;
  #pragma unroll
  for (int i=0;i<2;++i){ int q = tid + i*256; float e = (q<288)?expf(lv[i]-mx):0.f; lv[i]=e; s+=e; }
  s = block_sum(s, red);
  float inv = 1.f/s;
  #pragma unroll
  for (int i=0;i<2;++i){ int q = tid + i*256; if (q<288) row[q]=lv[i]*inv; }
}

// segmented softmax with folded SCOR Part (Ss slices) and CC Part (Sc slices)
__global__ __launch_bounds__(256) void k_softmax_seg(float* __restrict__ X, const float* __restrict__ PartS,
                                                     int Ss,
                                                     const float* __restrict__ CC,
                                                     const float* __restrict__ PartC, int Sc,
                                                     const int* __restrict__ SB, float scale){
  int r = blockIdx.x; int b = r>>4, qq = r&15;
  float* row = X + (long)r*1152;
  float bias[4];
  #pragma unroll
  for (int j=0;j<4;++j){
    int col = SB[b*4+j];
    float cv = CC[(long)r*32 + col];
    for (int s=0;s<Sc;++s) cv += PartC[(long)s*16384 + (long)r*32 + col];
    bias[j] = scale*cv;
  }
  int tid = threadIdx.x;
  __shared__ float red[8];
  float lv[5];
  #pragma unroll
  for (int i=0;i<5;++i){
    int q = tid + i*256;
    if (q<1152){
      float v = row[q];
      for (int s=0;s<Ss;++s) v += PartS[((long)s*32 + b)*18432 + (long)qq*1152 + q];
      lv[i] = v*scale + bias[q/288];
    } else lv[i] = -1e30f;
  }
  float mx = -1e30f;
  #pragma unroll
  for (int i=0;i<5;++i) mx = fmaxf(mx, lv[i]);
  mx = block_max(mx, red);
  float s = 0.f;
  #pragma unroll
  for (int i=0;i<5;++i){ int q = tid + i*256; float e = (q<1152)?expf(lv[i]-mx):0.f; lv[i]=e; s+=e; }
  s = block_sum(s, red);
  float inv = 1.f/s;
  #pragma unroll
  for (int i=0;i<5;++i){ int q = tid + i*256; if (q<1152) row[q]=lv[i]*inv; }
}

// F_REL finalize: sum PV parts, write final F_REL, row LN -> QLN planes
__global__ __launch_bounds__(256) void k_finalize_frel(float* __restrict__ F, const float* __restrict__ Part,
                                                       int S, __bf16* __restrict__ H, __bf16* __restrict__ L){
  int r = blockIdx.x;
  long ro = (long)r*2048;
  int tid = threadIdx.x;
  float4 vbuf[2];
  float s=0.f, s2=0.f;
  #pragma unroll
  for (int i=0;i<2;++i){
    long c = (long)tid*4 + i*1024;
    float4 a = *(const float4*)&F[ro+c];
    for (int ss=0; ss<S; ++ss){
      float4 p = *(const float4*)&Part[(long)ss*1048576 + ro + c];
      a.x += p.x; a.y += p.y; a.z += p.z; a.w += p.w;
    }
    vbuf[i] = a;
    *(float4*)&F[ro+c] = a;
    s  += a.x+a.y+a.z+a.w;
    s2 += a.x*a.x+a.y*a.y+a.z*a.z+a.w*a.w;
  }
  __shared__ float red[8];
  s  = block_sum(s,  red);
  s2 = block_sum(s2, red);
  float m = s*(1.f/2048.f);
  float var = s2*(1.f/2048.f) - m*m;
  float inv = rsqrtf(var + 1e-5f);
  #pragma unroll
  for (int i=0;i<2;++i){
    long c = (long)tid*4 + i*1024;
    float vv[4] = {vbuf[i].x, vbuf[i].y, vbuf[i].z, vbuf[i].w};
    bf16x4 h, l;
    #pragma unroll
    for (int e=0;e<4;++e){
      float y = (vv[e]-m)*inv;
      __bf16 hh = (__bf16)y;
      h[e] = hh;
      l[e] = (__bf16)(y - (float)hh);
    }
    *(bf16x4*)&H[ro+c] = h;
    *(bf16x4*)&L[ro+c] = l;
  }
}

// meanx + its rowstats fused: per-b block
__global__ __launch_bounds__(256) void k_meanx_stats(const float* __restrict__ frel, float* __restrict__ mx,
                                                     float* __restrict__ mu_m, float* __restrict__ m2_m){
  int b = blockIdx.x;
  const float* base = frel + (long)b*32768;
  int tid = threadIdx.x;
  float s=0.f, s2=0.f;
  #pragma unroll
  for (int i=0;i<2;++i){
    long c = (long)tid*4 + i*1024;
    float4 a = make_float4(0.f,0.f,0.f,0.f);
    #pragma unroll
    for (int q=0;q<16;++q){
      float4 v = *(const float4*)&base[(long)q*2048 + c];
      a.x += v.x; a.y += v.y; a.z += v.z; a.w += v.w;
    }
    a.x *= (1.f/16.f); a.y *= (1.f/16.f); a.z *= (1.f/16.f); a.w *= (1.f/16.f);
    *(float4*)&mx[(long)b*2048 + c] = a;
    s  += a.x+a.y+a.z+a.w;
    s2 += a.x*a.x+a.y*a.y+a.z*a.z+a.w*a.w;
  }
  __shared__ float red[8];
  s  = block_sum(s,  red);
  s2 = block_sum(s2, red);
  if (tid==0){ mu_m[b]=s*(1.f/2048.f); m2_m[b]=s2; }
}

// sigma with folded PM part slices
__global__ void k_sigma_r(const float* __restrict__ pm, const float* __restrict__ PartPM, int Sp,
                          const float* __restrict__ mu_p, const float* __restrict__ m2_p,
                          const float* __restrict__ mu_m, const float* __restrict__ m2_m,
                          float* __restrict__ sigma){
  int b = blockIdx.y; int n = blockIdx.x*256 + threadIdx.x;
  float pmv = pm[(long)b*2048+n];
  for (int s=0;s<Sp;++s) pmv += PartPM[(long)s*65536 + (long)b*2048 + n];
  float mp = mu_p[n], mm = mu_m[b];
  float vp = m2_p[n]*(1.f/2048.f) - mp*mp;
  float vm = m2_m[b]*(1.f/2048.f) - mm*mm;
  float cov = pmv*(1.f/2048.f) - mp*mm;
  sigma[(long)b*2048+n] = sqrtf(fmaxf(vp + vm - 2.f*cov, 0.f) + 1e-5f);
}

// fused: qm/qw dots (with folded MX parts + rank-1 fixrow algebra) + score softmax + QPW planes
__global__ __launch_bounds__(256) void k_score2f(const float* __restrict__ QP, const float* __restrict__ QPpart, int Sq,
                                                 const float* __restrict__ relq2,
                                                 const float* __restrict__ MX, const float* __restrict__ MXpart, int Sm,
                                                 const float* __restrict__ muw, const float* __restrict__ mu_m,
                                                 const float* __restrict__ sigma, const float* __restrict__ mu_p,
                                                 __bf16* __restrict__ QH, __bf16* __restrict__ QL,
                                                 float* __restrict__ W1, float* __restrict__ Wmu, float scale){
  int r = blockIdx.x; int b = r >> 4;
  int tid = threadIdx.x;
  __shared__ float red[8];
  // pass 1: qm = dot(relq2[r], MX_sum[b]); qw = dot(relq2[r], mu_w)
  float qm=0.f, qw=0.f;
  for (int c = tid*4; c < 2048; c += 1024){
    float4 va = *(const float4*)&relq2[(long)r*2048 + c];
    float4 vm = *(const float4*)&MX[(long)b*2048 + c];
    for (int s=0;s<Sm;++s){
      float4 p = *(const float4*)&MXpart[(long)s*65536 + (long)b*2048 + c];
      vm.x += p.x; vm.y += p.y; vm.z += p.z; vm.w += p.w;
    }
    float4 vw = *(const float4*)&muw[c];
    qm += va.x*vm.x+va.y*vm.y+va.z*vm.z+va.w*vm.w;
    qw += va.x*vw.x+va.y*vw.y+va.z*vw.z+va.w*vw.w;
  }
  qm = block_sum(qm, red);
  qw = block_sum(qw, red);
  float qmr = qm - 2048.f*mu_m[b]*qw;   // folds the deleted fixrow(MX)
  float qwr2048 = 2048.f*qw;
  const float* sg = sigma + (long)b*2048;
  float lv[8], ls[8], lmp[8];
  #pragma unroll
  for (int i=0;i<8;++i){
    int n = tid + i*256;
    float qpv = QP[(long)r*2048 + n];
    for (int s=0;s<Sq;++s) qpv += QPpart[(long)s*1048576 + (long)r*2048 + n];
    float sgn = sg[n];
    float mpn = mu_p[n];
    ls[i] = sgn;
    lmp[i] = mpn;
    lv[i] = scale * (qpv - qwr2048*mpn - qmr) / sgn;
  }
  float mx = -1e30f;
  #pragma unroll
  for (int i=0;i<8;++i) mx = fmaxf(mx, lv[i]);
  mx = block_max(mx, red);
  float se=0.f, sw=0.f, swm=0.f;
  #pragma unroll
  for (int i=0;i<8;++i){
    float e = expf(lv[i]-mx);
    lv[i] = e; se += e;
    float wv = e/ls[i];
    sw += wv; swm += wv*lmp[i];
  }
  se  = block_sum(se,  red);
  sw  = block_sum(sw,  red);
  swm = block_sum(swm, red);
  float inv = 1.f/se;
  #pragma unroll
  for (int i=0;i<8;++i){
    int n = tid + i*256;
    float v = lv[i]*inv/ls[i];
    __bf16 h = (__bf16)v;
    long idx = (long)r*2048 + n;
    QH[idx] = h;
    QL[idx] = (__bf16)(v - (float)h);
  }
  if (tid==0){ W1[r]=sw*inv; Wmu[r]=swm*inv; }
}

// fpro final: emits FPRO bf16 planes + fp32 weighted output
__global__ void k_fpro_final_s(const float* __restrict__ frel, const float* __restrict__ out2,
                               const float* __restrict__ meanx, const float* __restrict__ mu_m,
                               const float* __restrict__ W1, const float* __restrict__ Wmu,
                               const float* __restrict__ wsm,
                               __bf16* __restrict__ FH, __bf16* __restrict__ FL,
                               float* __restrict__ fout){
  int r = blockIdx.y; int c = blockIdx.x*256 + threadIdx.x;
  int b = r >> 4, q = r & 15;
  long idx = (long)r*2048 + c;
  float w1 = W1[r];
  float v = frel[idx] + out2[idx] - meanx[(long)b*2048+c]*w1 - Wmu[r] + mu_m[b]*w1;
  __bf16 h = (__bf16)v;
  FH[idx] = h;
  FL[idx] = (__bf16)(v - (float)h);
  fout[idx] = wsm[q] * v;
}

// cam embed gather -> bf16 hi/lo planes
__global__ void k_camb(const float* __restrict__ cam_table, const int* __restrict__ cam_ids,
                       __bf16* __restrict__ H, __bf16* __restrict__ L){
  int b = blockIdx.y; int c = blockIdx.x*256 + threadIdx.x;
  float v = cam_table[(long)(cam_ids[b]-1)*2048 + c];
  __bf16 h = (__bf16)v;
  long idx = (long)b*2048 + c;
  H[idx] = h;
  L[idx] = (__bf16)(v - (float)h);
}

// perm + gidx + SB + weight softmax (merged tiny kernels)
__global__ void k_permw(const void* __restrict__ subp, const float* __restrict__ w,
                        int* __restrict__ gidx, int* __restrict__ SB, float* __restrict__ wsm){
  __shared__ int perm[32];
  if (threadIdx.x==0){
    const int* pi = (const int*)subp;
    const float* pf = (const float*)subp;
    const unsigned char* pb = (const unsigned char*)subp;
    int sv[32]; bool okI=true, okF=true;
    for (int i=0;i<32;++i){ int v=pi[i]; if (v!=0 && v!=1) okI=false; }
    for (int i=0;i<32;++i){ float f=pf[i]; if (f!=0.f && f!=1.f) okF=false; }
    for (int i=0;i<32;++i){
      if (okI) sv[i]=pi[i];
      else if (okF) sv[i]=(pf[i]!=0.f)?1:0;
      else sv[i]=(pb[i]!=0)?1:0;
    }
    int pos=0;
    for (int i=0;i<32;++i) if (!sv[i]) perm[pos++]=i;
    for (int i=0;i<32;++i) if ( sv[i]) perm[pos++]=i;
    // weight softmax
    float mx=-1e30f;
    for (int i=0;i<16;++i) mx=fmaxf(mx,w[i]);
    float e[16], s=0.f;
    for (int i=0;i<16;++i){ e[i]=expf(w[i]-mx); s+=e[i]; }
    for (int i=0;i<16;++i) wsm[i]=e[i]/s;
  }
  __syncthreads();
  for (int i = threadIdx.x; i < 128; i += blockDim.x){
    int b = i>>2, j = i&3;
    SB[i] = ((perm[b]>>2)<<2) + j;
  }
  for (int idx = threadIdx.x; idx < 32*1152; idx += blockDim.x){
    int b = idx / 1152, rem = idx % 1152, j = rem / 288, n = rem % 288;
    int src = ((perm[b] >> 2) << 2) + j;
    gidx[idx] = src*288 + n;
  }
}

// ---------------- launcher ----------------
extern "C" void kernel_launch(void* const* d_in, const int* in_sizes, int n_in,
                              void* d_out, int out_size, void* d_ws, size_t ws_size,
                              hipStream_t stream) {
  const float* x        = (const float*)d_in[0];   // [32,2048,288]
  const int*   cam_ids  = (const int*)d_in[1];
  const void*  subp     = d_in[2];
  const float* query_v  = (const float*)d_in[3];   // [16,2048]
  const float* proto    = (const float*)d_in[4];   // [2048,2048]
  const float* weights  = (const float*)d_in[5];   // [16]
  const float* cam_tab  = (const float*)d_in[6];   // [6,2048]
  const float* Wcq      = (const float*)d_in[8];
  const float* Wcg      = (const float*)d_in[9];
  const float* Wdq      = (const float*)d_in[10];
  const float* Wdg      = (const float*)d_in[11];
  float* out = (float*)d_out;
  float* ws  = (float*)d_ws;

  size_t o = 0;
  float* S     = ws + o; o += 2654208;   // S fp32 (gram out); later hosts QLN/RELQ2 planes
  __bf16* QLNh   = (__bf16*)S;
  __bf16* QLNl   = (__bf16*)(S + 524288);
  __bf16* RELQ2h = (__bf16*)(S + 1048576);
  __bf16* RELQ2l = (__bf16*)(S + 1572864);
  float* XSR   = ws + o; o += 18874368;  // XS planes; then S planes + PART + weight planes
  __bf16* XSh = (__bf16*)XSR;
  __bf16* XSl = XSh + 18874368;
  __bf16* Shp = (__bf16*)XSR;            // S planes (after gram consumed XS planes)
  __bf16* Slp = Shp + 2654208;
  float* PART  = XSR;                    // [0, 6.29M) floats
  __bf16* WCQh  = (__bf16*)(XSR + 6291456);
  __bf16* WCQl  = (__bf16*)(XSR + 8388608);
  __bf16* WCGTh = (__bf16*)(XSR + 10485760);
  __bf16* WCGTl = (__bf16*)(XSR + 12582912);
  __bf16* ROTh  = (__bf16*)(XSR + 14680064);
  __bf16* ROTl  = (__bf16*)(XSR + 16777216);
  float* GMIXR = ws + o; o += 18874368;  // gram Part, then GMIX planes
  __bf16* GMIXh = (__bf16*)GMIXR;
  __bf16* GMIXl = GMIXh + 18874368;
  float* M2_XS = ws + o; o += 9216;
  float* CAMB  = ws + o; o += 65536;
  __bf16* CAMBh = (__bf16*)CAMB;
  __bf16* CAMBl = CAMBh + 65536;
  float* RQ0   = ws + o; o += 32768;
  float* RQW   = ws + o; o += 32768;
  float* SREL  = ws + o; o += 147456;
  float* T1    = ws + o; o += 1048576;
  float* RELQ2 = ws + o; o += 1048576;
  float* MEANX = ws + o; o += 65536;
  float* MU_P  = ws + o; o += 2048;
  float* M2_P  = ws + o; o += 2048;
  float* MU_M  = ws + o; o += 64;
  float* M2_M  = ws + o; o += 64;
  float* MU_W  = ws + o; o += 2048;
  float* M2_W  = ws + o; o += 2048;
  float* PM    = ws + o; o += 65536;
  float* SIGMA = ws + o; o += 65536;
  float* MX    = ws + o; o += 65536;
  float* QP    = ws + o; o += 1048576;
  float* W1    = ws + o; o += 512;
  float* WMU   = ws + o; o += 512;
  float* OUT2  = ws + o; o += 1048576;
  __bf16* FPROh = (__bf16*)(ws + o);
  __bf16* FPROl = (__bf16*)(ws + o + 524288); o += 1048576;
  float* RQ2   = ws + o; o += 1048576;
  float* RQW2  = ws + o; o += 1048576;
  __bf16* RQW2h = (__bf16*)(ws + o);
  __bf16* RQW2l = RQW2h + 1048576; o += 1048576;
  float* SREC  = ws + o; o += 147456;
  float* SCOR  = ws + o; o += 589824;
  float* CC    = ws + o; o += 16384;
  float* WSM   = ws + o; o += 16;
  __bf16* T1h   = (__bf16*)(ws + o);
  __bf16* T1l   = (__bf16*)(ws + o + 524288); o += 1048576;
  __bf16* QPWh  = (__bf16*)(ws + o);
  __bf16* QPWl  = (__bf16*)(ws + o + 524288); o += 1048576;
  __bf16* RQ2h  = (__bf16*)(ws + o);
  __bf16* RQ2l  = (__bf16*)(ws + o + 524288); o += 1048576;
  __bf16* QVh   = (__bf16*)(ws + o);
  __bf16* QVl   = (__bf16*)(ws + o + 16384); o += 32768;
  __bf16* RQ0h  = (__bf16*)(ws + o);
  __bf16* RQ0l  = (__bf16*)(ws + o + 16384); o += 32768;
  __bf16* RQWh  = (__bf16*)(ws + o);
  __bf16* RQWl  = RQWh + 32768; o += 32768;
  int*   GIDX  = (int*)(ws + o); o += 36864;
  int*   SB    = (int*)(ws + o); o += 128;

  float* F_REL = out;
  float* F_PRO = out + 1048576;
  float* F_REC = out + 2097152;
  float* F_COR = out + 3145728;

  float* PART_CC = PART + 4000000;   // CC slices (7 x 16384)
  float* PART_MX = PART + 3145728;   // MX slices (7 x 65536), survives QP's [0,2M)

  // ---- Phase A ----
  hipMemsetAsync(M2_XS, 0, 9216*sizeof(float), stream);
  k_trs<<<dim3(9,64,32), dim3(32,8), 0, stream>>>(x, XSh, XSl, M2_XS);
  gemm_nt_bsg<3,3,2,2><<<576, 256, 0, stream>>>(S, XSh,XSl, XSh,XSl,
      288,288,2048, 2048,2048,288, 589824,589824,82944, 1.f, nullptr,0, 3,3,64, 2, GMIXR);
  k_softmax_gram_s<<<9216, 256, 0, stream>>>(S, GMIXR, M2_XS, Shp, Slp);
  gemm_gmix<<<1536, 256, 0, stream>>>(Shp, Slp, x, GMIXh, GMIXl);
  k_split<<<2048, 256, 0, stream>>>(Wcq, WCQh, WCQl, 4194304L);
  k_tr_split<<<dim3(64,64), dim3(32,8), 0, stream>>>(Wcg, WCGTh, WCGTl, 2048, 2048);
  k_split<<<32, 256, 0, stream>>>(query_v, QVh, QVl, 32768L);
  k_camb<<<dim3(8,32), 256, 0, stream>>>(cam_tab, cam_ids, CAMBh, CAMBl);
  k_permw<<<1, 256, 0, stream>>>(subp, weights, GIDX, SB, WSM);

  // ---- f_rel ----
  gemm_nt_bsg<1,4,1,4><<<128, 256, 0, stream>>>(RQ0, QVh,QVl, WCQh,WCQl,
      16,2048,2048, 2048,2048,2048, 0,0,0, 1.f, nullptr,0, 8,1,16, 16, PART);
  k_reduce_split<<<64, 256, 0, stream>>>(RQ0, PART, 32768L, 15, 1.f, RQ0h, RQ0l);
  gemm_nt_bsg<1,4,1,4><<<128, 256, 0, stream>>>(RQW, RQ0h,RQ0l, WCGTh,WCGTl,
      16,2048,2048, 2048,2048,2048, 0,0,0, 1.f, nullptr,0, 8,1,16, 16, PART);
  k_reduce_split<<<64, 256, 0, stream>>>(RQW, PART, 32768L, 15, 1.f, RQWh, RQWl);
  gemm_nt_bsg<1,4,1,4><<<512, 256, 0, stream>>>(SREL, RQWh,RQWl, GMIXh,GMIXl,
      16,288,2048, 2048,2048,288, 0,589824,4608, SCALE, nullptr,0, 2,1,256, 8, PART);
  k_softmax_plain_r<<<512, 256, 0, stream>>>(SREL, PART, 7, SCALE);
  k_pv2<<<dim3(4,32,7), 256, 16*44*4, stream>>>(F_REL, PART, SREL, 4608, 288, 44,
      GMIXh, GMIXl, 589824, nullptr);
  k_finalize_frel<<<512, 256, 0, stream>>>(F_REL, PART, 6, QLNh, QLNl);

  // ---- deltaor ----
  k_meanx_stats<<<32, 256, 0, stream>>>(F_REL, MEANX, MU_M, M2_M);
  k_rowstats2<<<4096, 256, 0, stream>>>(proto, Wdg, MU_P, M2_P, MU_W, M2_W);
  k_split<<<2048, 256, 0, stream>>>(Wdq, ROTh, ROTl, 4194304L);
  gemm_nt_bsg<2,2,2,2><<<768, 256, 0, stream>>>(RELQ2, QLNh,QLNl, ROTh,ROTl,
      512,2048,2048, 2048,2048,2048, 0,0,0, 1.f, nullptr,0, 32,8,3, 3, PART);
  k_reduce_split<<<1024, 256, 0, stream>>>(RELQ2, PART, 1048576L, 2, 1.f, RELQ2h, RELQ2l);
  gemm_nt_mfma<1,4,1,4><<<dim3(8,2,8), 256, 0, stream>>>(PM, MEANX, proto, 32,2048,2048,
      2048,2048,2048, 0,0,0, 1.f, 8, PART);
  k_sigma_r<<<dim3(8,32), 256, 0, stream>>>(PM, PART, 7, MU_P, M2_P, MU_M, M2_M, SIGMA);
  k_tr_split<<<dim3(64,64), dim3(32,8), 0, stream>>>(Wdg, ROTh, ROTl, 2048, 2048);  // WDGT
  gemm_nt_bsg<2,2,2,2><<<768, 256, 0, stream>>>(T1, RELQ2h,RELQ2l, ROTh,ROTl,
      512,2048,2048, 2048,2048,2048, 0,0,0, 1.f, nullptr,0, 32,8,3, 3, PART);
  k_reduce_split<<<1024, 256, 0, stream>>>(T1, PART, 1048576L, 2, 1.f, T1h, T1l);
  gemm_nt_mfma<1,4,1,4><<<dim3(8,2,8), 256, 0, stream>>>(MX, MEANX, Wdg, 32,2048,2048,
      2048,2048,2048, 0,0,0, 1.f, 8, PART_MX);
  k_split<<<2048, 256, 0, stream>>>(proto, ROTh, ROTl, 4194304L);
  gemm_nt_bsg<2,2,2,2><<<768, 256, 0, stream>>>(QP, T1h,T1l, ROTh,ROTl,
      512,2048,2048, 2048,2048,2048, 0,0,0, 1.f, nullptr,0, 32,8,3, 3, PART);
  k_score2f<<<512, 256, 0, stream>>>(QP, PART, 2, RELQ2, MX, PART_MX, 7,
      MU_W, MU_M, SIGMA, MU_P, QPWh, QPWl, W1, WMU, SCALE);
  k_tr_split<<<dim3(64,64), dim3(32,8), 0, stream>>>(proto, ROTh, ROTl, 2048, 2048); // PROTOT
  gemm_nt_bsg<2,2,2,2><<<768, 256, 0, stream>>>(OUT2, QPWh,QPWl, ROTh,ROTl,
      512,2048,2048, 2048,2048,2048, 0,0,0, 1.f, nullptr,0, 32,8,3, 3, PART);
  k_reduce4<<<1024, 256, 0, stream>>>(OUT2, PART, 1048576L, 2, 1.f);
  k_fpro_final_s<<<dim3(8,512), 256, 0, stream>>>(F_REL, OUT2, MEANX, MU_M, W1, WMU, WSM,
                                                  FPROh, FPROl, F_PRO);

  // ---- f_rec ----
  gemm_nt_bsg<2,2,2,2><<<768, 256, 0, stream>>>(RQ2, FPROh,FPROl, WCQh,WCQl,
      512,2048,2048, 2048,2048,2048, 0,0,0, 1.f, nullptr,0, 32,8,3, 3, PART);
  k_reduce_split<<<1024, 256, 0, stream>>>(RQ2, PART, 1048576L, 2, 1.f, RQ2h, RQ2l);
  gemm_nt_bsg<2,2,2,2><<<768, 256, 0, stream>>>(RQW2, RQ2h,RQ2l, WCGTh,WCGTl,
      512,2048,2048, 2048,2048,2048, 0,0,0, 1.f, nullptr,0, 32,8,3, 3, PART);
  k_reduce_split<<<1024, 256, 0, stream>>>(RQW2, PART, 1048576L, 2, 1.f, RQW2h, RQW2l);
  gemm_nt_bsg<1,4,1,4><<<512, 256, 0, stream>>>(SREC, RQW2h,RQW2l, GMIXh,GMIXl,
      16,288,2048, 2048,2048,288, 32768,589824,4608, SCALE, nullptr,0, 2,1,256, 8, PART);
  k_softmax_plain_r<<<512, 256, 0, stream>>>(SREC, PART, 7, SCALE);
  k_pv2<<<dim3(4,32,7), 256, 16*44*4, stream>>>(F_REC, PART, SREC, 4608, 288, 44,
      GMIXh, GMIXl, 589824, nullptr);
  k_reduce4<<<1024, 256, 0, stream>>>(F_REC, PART, 1048576L, 6, 1.f);

  // ---- f_cor ----
  gemm_nt_bsg<1,4,1,4><<<256, 256, 0, stream>>>(CC, RQW2h,RQW2l, CAMBh,CAMBl,
      512,32,2048, 2048,2048,32, 0,0,0, 1.f, nullptr,0, 1,32,8, 8, PART_CC);
  gemm_nt_bsg<1,4,1,4><<<640, 256, 0, stream>>>(SCOR, RQW2h,RQW2l, GMIXh,GMIXl,
      16,1152,2048, 2048,2048,1152, 32768,0,18432, SCALE, GIDX,1152, 5,1,128, 4, PART);
  k_softmax_seg<<<512, 256, 0, stream>>>(SCOR, PART, 3, CC, PART_CC, 7, SB, SCALE);
  k_pv2<<<dim3(4,32,7), 256, 16*168*4, stream>>>(F_COR, PART, SCOR, 18432, 1152, 168,
      GMIXh, GMIXl, 589824, SB);
  k_reduce4<<<1024, 256, 0, stream>>>(F_COR, PART, 1048576L, 6, 1.f);
}

// Round 9
// 913.094 us; speedup vs baseline: 1.0115x; 1.0115x over previous
//
#include <hip/hip_runtime.h>
#include <math.h>

// B=32, C=2048, N=288(==PATCH), Q=16, proto tokens=2048
static constexpr float SCALE = 0.022097086912079612f; // 2048^-0.5

typedef __bf16 bf16x2 __attribute__((ext_vector_type(2)));
typedef __bf16 bf16x4 __attribute__((ext_vector_type(4)));
typedef __bf16 bf16x8 __attribute__((ext_vector_type(8)));
typedef float  f32x2  __attribute__((ext_vector_type(2)));
typedef float  f32x4  __attribute__((ext_vector_type(4)));

// ---------------- reduction helpers ----------------
__device__ __forceinline__ float wred_sum(float v){
  #pragma unroll
  for (int o=32;o>0;o>>=1) v += __shfl_down(v,o,64);
  return v;
}
__device__ __forceinline__ float wred_max(float v){
  #pragma unroll
  for (int o=32;o>0;o>>=1) v = fmaxf(v, __shfl_down(v,o,64));
  return v;
}
__device__ __forceinline__ float block_sum(float v, float* red){
  int tid=threadIdx.x, w=tid>>6, l=tid&63, nw=(int)(blockDim.x>>6);
  v = wred_sum(v);
  __syncthreads();
  if (l==0) red[w]=v;
  __syncthreads();
  float r=0.f;
  for (int i=0;i<nw;i++) r += red[i];
  return r;
}
__device__ __forceinline__ float block_max(float v, float* red){
  int tid=threadIdx.x, w=tid>>6, l=tid&63, nw=(int)(blockDim.x>>6);
  v = wred_max(v);
  __syncthreads();
  if (l==0) red[w]=v;
  __syncthreads();
  float r=red[0];
  for (int i=1;i<nw;i++) r = fmaxf(r, red[i]);
  return r;
}

// ---------------- MFMA split-bf16 NT GEMM (fp32 inputs), Part split-K ----------------
template<int MT, int NT, int WM, int WN>
__global__ __launch_bounds__(256, 2)
void gemm_nt_mfma(float* __restrict__ Cm, const float* __restrict__ Am,
                  const float* __restrict__ Bm, int M, int N, int K,
                  int lda, int ldb, int ldc, long sA, long sB, long sC,
                  float alpha, int KS, float* __restrict__ Part)
{
  constexpr int BM = MT*16*WM;
  constexpr int BN = NT*16*WN;
  constexpr int LDH = 40;
  constexpr int AST = (BM+31)/32;
  constexpr int BST = (BN+31)/32;
  __shared__ __bf16 Ah[BM*LDH];
  __shared__ __bf16 Al[BM*LDH];
  __shared__ __bf16 Bh[BN*LDH];
  __shared__ __bf16 Bl[BN*LDH];
  int ZZ = gridDim.z / KS;
  int z  = blockIdx.z % ZZ;
  int ks = blockIdx.z / ZZ;
  const float* A = Am + (long)z*sA;
  const float* B = Bm + (long)z*sB;
  float* C = Cm + (long)z*sC;
  int Kc = ((K + KS*32 - 1) / (KS*32)) * 32;
  int kbeg = ks*Kc;
  int kend = min(K, kbeg + Kc);
  int m0 = blockIdx.y*BM, n0 = blockIdx.x*BN;
  int t = threadIdx.x;
  int srow = t>>3, skoff = (t&7)*4;

  float4 areg[AST], breg[BST];
  auto loadAB = [&](int k0){
    #pragma unroll
    for (int s=0;s<AST;++s){
      int row = srow + 32*s; int gm = m0+row;
      areg[s] = make_float4(0.f,0.f,0.f,0.f);
      if (row < BM && gm < M) areg[s] = *(const float4*)(A + (long)gm*lda + k0 + skoff);
    }
    #pragma unroll
    for (int s=0;s<BST;++s){
      int row = srow + 32*s; int gn = n0+row;
      breg[s] = make_float4(0.f,0.f,0.f,0.f);
      if (row < BN && gn < N) breg[s] = *(const float4*)(B + (long)gn*ldb + k0 + skoff);
    }
  };
  auto writeLDS = [&](){
    #pragma unroll
    for (int s=0;s<AST;++s){
      int row = srow + 32*s;
      if (row < BM){
        float vv[4] = {areg[s].x, areg[s].y, areg[s].z, areg[s].w};
        bf16x4 hv, lv;
        #pragma unroll
        for (int e=0;e<4;++e){
          __bf16 h = (__bf16)vv[e];
          hv[e] = h;
          lv[e] = (__bf16)(vv[e] - (float)h);
        }
        *(bf16x4*)&Ah[row*LDH + skoff] = hv;
        *(bf16x4*)&Al[row*LDH + skoff] = lv;
      }
    }
    #pragma unroll
    for (int s=0;s<BST;++s){
      int row = srow + 32*s;
      if (row < BN){
        float vv[4] = {breg[s].x, breg[s].y, breg[s].z, breg[s].w};
        bf16x4 hv, lv;
        #pragma unroll
        for (int e=0;e<4;++e){
          __bf16 h = (__bf16)vv[e];
          hv[e] = h;
          lv[e] = (__bf16)(vv[e] - (float)h);
        }
        *(bf16x4*)&Bh[row*LDH + skoff] = hv;
        *(bf16x4*)&Bl[row*LDH + skoff] = lv;
      }
    }
  };

  int lane = t & 63, wid = t >> 6;
  int wm = (WM==1) ? 0 : (wid / WN);
  int wn = wid % WN;
  int mw = wm*MT*16, nw = wn*NT*16;
  int fr = lane & 15, fq = (lane>>4)*8;

  f32x4 acc[MT][NT];
  #pragma unroll
  for (int i=0;i<MT;++i)
    #pragma unroll
    for (int j=0;j<NT;++j) acc[i][j] = (f32x4){0.f,0.f,0.f,0.f};

  if (kbeg < kend) loadAB(kbeg);
  for (int k0=kbeg; k0<kend; k0+=32){
    writeLDS();
    __syncthreads();
    if (k0+32 < kend) loadAB(k0+32);
    bf16x8 ah[MT], al[MT], bh[NT], bl[NT];
    #pragma unroll
    for (int i=0;i<MT;++i){
      ah[i] = *(const bf16x8*)&Ah[(mw+i*16+fr)*LDH + fq];
      al[i] = *(const bf16x8*)&Al[(mw+i*16+fr)*LDH + fq];
    }
    #pragma unroll
    for (int j=0;j<NT;++j){
      bh[j] = *(const bf16x8*)&Bh[(nw+j*16+fr)*LDH + fq];
      bl[j] = *(const bf16x8*)&Bl[(nw+j*16+fr)*LDH + fq];
    }
    #pragma unroll
    for (int i=0;i<MT;++i)
      #pragma unroll
      for (int j=0;j<NT;++j){
        acc[i][j] = __builtin_amdgcn_mfma_f32_16x16x32_bf16(ah[i], bh[j], acc[i][j], 0,0,0);
        acc[i][j] = __builtin_amdgcn_mfma_f32_16x16x32_bf16(ah[i], bl[j], acc[i][j], 0,0,0);
        acc[i][j] = __builtin_amdgcn_mfma_f32_16x16x32_bf16(al[i], bh[j], acc[i][j], 0,0,0);
      }
    __syncthreads();
  }
  float wf = (KS==1) ? alpha : 1.f;
  float* Cw = C; int ldw = ldc;
  if (ks > 0){ Cw = Part + ((long)(ks-1)*ZZ + z)*(long)M*N; ldw = N; }
  int er = (lane>>4)*4, ec = lane & 15;
  #pragma unroll
  for (int i=0;i<MT;++i){
    int mbase = m0 + mw + i*16 + er;
    #pragma unroll
    for (int r=0;r<4;++r){
      int mm = mbase + r;
      if (mm < M){
        long cro = (long)mm*ldw;
        #pragma unroll
        for (int j=0;j<NT;++j){
          int nn = n0 + nw + j*16 + ec;
          if (nn < N) Cw[cro + nn] = wf*acc[i][j][r];
        }
      }
    }
  }
}

// ---------------- MFMA NT GEMM on pre-split bf16 hi/lo planes (batched + gather) ----------------
// Flat 1D grid with chunked XCD swizzle: blocks sharing an A-panel (same y,z)
// get consecutive in-XCD slots so each XCD's L2 fetches shared panels once.
template<int MT, int NT, int WM, int WN>
__global__ __launch_bounds__(256, 4)
void gemm_nt_bsg(float* __restrict__ Cm,
                 const __bf16* __restrict__ Ahg, const __bf16* __restrict__ Alg,
                 const __bf16* __restrict__ Bhg, const __bf16* __restrict__ Blg,
                 int M, int N, int K, int lda, int ldb, int ldc,
                 long sA, long sB, long sC,
                 float alpha, const int* __restrict__ browidx, long sBrow,
                 int SX, int SY, int SZ, int KS, float* __restrict__ Part)
{
  constexpr int BM = MT*16*WM;
  constexpr int BN = NT*16*WN;
  constexpr int LDH = 40;
  __shared__ __bf16 Ah[BM*LDH];
  __shared__ __bf16 Al[BM*LDH];
  __shared__ __bf16 Bh[BN*LDH];
  __shared__ __bf16 Bl[BN*LDH];
  int total = SX*SY*SZ;
  int bid = blockIdx.x;
  int w = (bid & 7)*(total >> 3) + (bid >> 3);   // chunked XCD transform (total%8==0)
  int bx = w % SX; int g = w / SX;
  int by = g % SY; int bz = g / SY;
  int ZZ = SZ / KS;
  int z  = bz % ZZ;
  int ks = bz / ZZ;
  const __bf16* Ahb = Ahg + (long)z*sA;
  const __bf16* Alb = Alg + (long)z*sA;
  const __bf16* Bhb = Bhg + (long)z*sB;
  const __bf16* Blb = Blg + (long)z*sB;
  float* C = Cm + (long)z*sC;
  const bool useB = (browidx != nullptr);
  const int* brow = useB ? (browidx + (long)z*sBrow) : nullptr;
  int Kc = ((K + KS*32 - 1) / (KS*32)) * 32;
  int kbeg = ks*Kc;
  int kend = min(K, kbeg + Kc);
  int m0 = by*BM, n0 = bx*BN;
  int t = threadIdx.x;
  constexpr int ASl = (BM*4 + 255)/256;
  constexpr int BSl = (BN*4 + 255)/256;
  bf16x8 arh[ASl], arl[ASl], brh[BSl], brl[BSl];
  bf16x8 zed;
  #pragma unroll
  for (int e=0;e<8;++e) zed[e] = (__bf16)0.f;

  auto loadAB = [&](int k0){
    #pragma unroll
    for (int i=0;i<ASl;++i){
      int s = t + 256*i;
      arh[i] = zed; arl[i] = zed;
      if (s < BM*4){
        int row = s>>2, koff = (s&3)*8; int gm = m0+row;
        if (gm < M){
          long off = (long)gm*lda + k0 + koff;
          arh[i] = *(const bf16x8*)(Ahb + off);
          arl[i] = *(const bf16x8*)(Alb + off);
        }
      }
    }
    #pragma unroll
    for (int i=0;i<BSl;++i){
      int s = t + 256*i;
      brh[i] = zed; brl[i] = zed;
      if (s < BN*4){
        int row = s>>2, koff = (s&3)*8; int gn = n0+row;
        if (gn < N){
          long r = useB ? (long)brow[gn] : (long)gn;
          long off = r*ldb + k0 + koff;
          brh[i] = *(const bf16x8*)(Bhb + off);
          brl[i] = *(const bf16x8*)(Blb + off);
        }
      }
    }
  };
  auto writeLDS = [&](){
    #pragma unroll
    for (int i=0;i<ASl;++i){
      int s = t + 256*i;
      if (s < BM*4){
        int row = s>>2, koff = (s&3)*8;
        *(bf16x8*)&Ah[row*LDH + koff] = arh[i];
        *(bf16x8*)&Al[row*LDH + koff] = arl[i];
      }
    }
    #pragma unroll
    for (int i=0;i<BSl;++i){
      int s = t + 256*i;
      if (s < BN*4){
        int row = s>>2, koff = (s&3)*8;
        *(bf16x8*)&Bh[row*LDH + koff] = brh[i];
        *(bf16x8*)&Bl[row*LDH + koff] = brl[i];
      }
    }
  };

  int lane = t & 63, wid = t >> 6;
  int wm = (WM==1) ? 0 : (wid / WN);
  int wn = wid % WN;
  int mw = wm*MT*16, nw = wn*NT*16;
  int fr = lane & 15, fq = (lane>>4)*8;

  f32x4 acc[MT][NT];
  #pragma unroll
  for (int i=0;i<MT;++i)
    #pragma unroll
    for (int j=0;j<NT;++j) acc[i][j] = (f32x4){0.f,0.f,0.f,0.f};

  if (kbeg < kend) loadAB(kbeg);
  for (int k0=kbeg; k0<kend; k0+=32){
    writeLDS();
    __syncthreads();
    if (k0+32 < kend) loadAB(k0+32);
    bf16x8 ah[MT], al[MT], bh[NT], bl[NT];
    #pragma unroll
    for (int i=0;i<MT;++i){
      ah[i] = *(const bf16x8*)&Ah[(mw+i*16+fr)*LDH + fq];
      al[i] = *(const bf16x8*)&Al[(mw+i*16+fr)*LDH + fq];
    }
    #pragma unroll
    for (int j=0;j<NT;++j){
      bh[j] = *(const bf16x8*)&Bh[(nw+j*16+fr)*LDH + fq];
      bl[j] = *(const bf16x8*)&Bl[(nw+j*16+fr)*LDH + fq];
    }
    #pragma unroll
    for (int i=0;i<MT;++i)
      #pragma unroll
      for (int j=0;j<NT;++j){
        acc[i][j] = __builtin_amdgcn_mfma_f32_16x16x32_bf16(ah[i], bh[j], acc[i][j], 0,0,0);
        acc[i][j] = __builtin_amdgcn_mfma_f32_16x16x32_bf16(ah[i], bl[j], acc[i][j], 0,0,0);
        acc[i][j] = __builtin_amdgcn_mfma_f32_16x16x32_bf16(al[i], bh[j], acc[i][j], 0,0,0);
      }
    __syncthreads();
  }
  float wf = (KS==1) ? alpha : 1.f;
  float* Cw = C; int ldw = ldc;
  if (ks > 0){ Cw = Part + ((long)(ks-1)*ZZ + z)*(long)M*N; ldw = N; }
  int er = (lane>>4)*4, ec = lane & 15;
  #pragma unroll
  for (int i=0;i<MT;++i){
    int mbase = m0 + mw + i*16 + er;
    #pragma unroll
    for (int r=0;r<4;++r){
      int mm = mbase + r;
      if (mm < M){
        long cro = (long)mm*ldw;
        #pragma unroll
        for (int j=0;j<NT;++j){
          int nn = n0 + nw + j*16 + ec;
          if (nn < N) Cw[cro + nn] = wf*acc[i][j][r];
        }
      }
    }
  }
}

// ---------------- GMIX GEMM: A = S planes, B = x fp32 (convert), C = planes out ----------------
// Conceptual grid 16x3x32, flat-launched with chunked XCD swizzle.
// Epilogue stages each bf16 plane tile in LDS, then stores coalesced 16B lines
// (scalar bf16 stores caused 2.3x write amplification at occupancy 4).
__global__ __launch_bounds__(256, 4)
void gemm_gmix(const __bf16* __restrict__ Sh, const __bf16* __restrict__ Sl,
               const float* __restrict__ xg,
               __bf16* __restrict__ Gh, __bf16* __restrict__ Gl)
{
  constexpr int BM = 96, BN = 128, LDH = 40;
  __shared__ __bf16 smem[2*(BM+BN)*LDH];   // 17920 elems = 35840B
  __bf16* Ah = smem;
  __bf16* Al = smem + BM*LDH;
  __bf16* Bh = smem + 2*BM*LDH;
  __bf16* Bl = smem + 2*BM*LDH + BN*LDH;
  int bid = blockIdx.x;
  int w = (bid & 7)*192 + (bid >> 3);   // total 1536
  int bx = w % 16; int g = w / 16;
  int by = g % 3;  int z = g / 3;
  const __bf16* Azh = Sh + (long)z*82944;
  const __bf16* Azl = Sl + (long)z*82944;
  const float*  B   = xg + (long)z*589824;
  int m0 = by*BM, n0 = bx*BN;
  int t = threadIdx.x;
  int srow = t>>3, skoff = (t&7)*4;
  bf16x8 arh[2], arl[2];
  float4 breg[4];
  auto loadAB = [&](int k0){
    #pragma unroll
    for (int i=0;i<2;++i){
      int s = t + 256*i;
      if (s < 384){
        int row = s>>2, koff = (s&3)*8;
        long off = (long)(m0+row)*288 + k0 + koff;
        arh[i] = *(const bf16x8*)(Azh + off);
        arl[i] = *(const bf16x8*)(Azl + off);
      }
    }
    #pragma unroll
    for (int si=0;si<4;++si){
      int row = srow + 32*si;
      breg[si] = *(const float4*)(B + (long)(n0+row)*288 + k0 + skoff);
    }
  };
  auto writeLDS = [&](){
    #pragma unroll
    for (int i=0;i<2;++i){
      int s = t + 256*i;
      if (s < 384){
        int row = s>>2, koff = (s&3)*8;
        *(bf16x8*)&Ah[row*LDH + koff] = arh[i];
        *(bf16x8*)&Al[row*LDH + koff] = arl[i];
      }
    }
    #pragma unroll
    for (int si=0;si<4;++si){
      int row = srow + 32*si;
      float vv[4] = {breg[si].x, breg[si].y, breg[si].z, breg[si].w};
      bf16x4 hv, lv;
      #pragma unroll
      for (int e=0;e<4;++e){
        __bf16 h = (__bf16)vv[e];
        hv[e] = h;
        lv[e] = (__bf16)(vv[e] - (float)h);
      }
      *(bf16x4*)&Bh[row*LDH + skoff] = hv;
      *(bf16x4*)&Bl[row*LDH + skoff] = lv;
    }
  };
  int lane = t & 63, wid = t >> 6;
  int wm = wid >> 1, wn = wid & 1;
  int mw = wm*48, nw = wn*64;
  int fr = lane & 15, fq = (lane>>4)*8;
  f32x4 acc[3][4];
  #pragma unroll
  for (int i=0;i<3;++i)
    #pragma unroll
    for (int j=0;j<4;++j) acc[i][j] = (f32x4){0.f,0.f,0.f,0.f};

  loadAB(0);
  for (int k0=0; k0<288; k0+=32){
    writeLDS();
    __syncthreads();
    if (k0+32 < 288) loadAB(k0+32);
    bf16x8 ah[3], al[3], bh[4], bl[4];
    #pragma unroll
    for (int i=0;i<3;++i){
      ah[i] = *(const bf16x8*)&Ah[(mw+i*16+fr)*LDH + fq];
      al[i] = *(const bf16x8*)&Al[(mw+i*16+fr)*LDH + fq];
    }
    #pragma unroll
    for (int j=0;j<4;++j){
      bh[j] = *(const bf16x8*)&Bh[(nw+j*16+fr)*LDH + fq];
      bl[j] = *(const bf16x8*)&Bl[(nw+j*16+fr)*LDH + fq];
    }
    #pragma unroll
    for (int i=0;i<3;++i)
      #pragma unroll
      for (int j=0;j<4;++j){
        acc[i][j] = __builtin_amdgcn_mfma_f32_16x16x32_bf16(ah[i], bh[j], acc[i][j], 0,0,0);
        acc[i][j] = __builtin_amdgcn_mfma_f32_16x16x32_bf16(ah[i], bl[j], acc[i][j], 0,0,0);
        acc[i][j] = __builtin_amdgcn_mfma_f32_16x16x32_bf16(al[i], bh[j], acc[i][j], 0,0,0);
      }
    __syncthreads();
  }
  // ---- staged coalesced epilogue: smem free after final barrier ----
  int er = (lane>>4)*4, ec = lane & 15;
  #pragma unroll
  for (int pl=0; pl<2; ++pl){
    #pragma unroll
    for (int i=0;i<3;++i){
      #pragma unroll
      for (int r=0;r<4;++r){
        int rloc = mw + i*16 + er + r;
        #pragma unroll
        for (int j=0;j<4;++j){
          int cloc = nw + j*16 + ec;
          float v = acc[i][j][r];
          __bf16 h = (__bf16)v;
          smem[rloc*BN + cloc] = (pl==0) ? h : (__bf16)(v - (float)h);
        }
      }
    }
    __syncthreads();
    __bf16* plane = (pl==0) ? Gh : Gl;
    for (int it = t; it < (BM*BN)/8; it += 256){
      int row = it >> 4;           // BN/8 = 16 chunks per row
      int col = (it & 15)*8;
      long go = (long)z*589824 + (long)(m0+row)*2048 + n0 + col;
      *(bf16x8*)&plane[go] = *(const bf16x8*)&smem[row*BN + col];
    }
    __syncthreads();
  }
}

// C[i] = alpha * (C[i] + sum parts), float4
__global__ __launch_bounds__(256) void k_reduce4(float* __restrict__ C, const float* __restrict__ Part,
                                                 long total, int S, float alpha){
  long n4 = total >> 2;
  for (long i = (long)blockIdx.x*blockDim.x + threadIdx.x; i < n4;
       i += (long)gridDim.x*blockDim.x){
    float4 v = ((float4*)C)[i];
    for (int s=0;s<S;++s){
      float4 p = ((const float4*)(Part + (long)s*total))[i];
      v.x += p.x; v.y += p.y; v.z += p.z; v.w += p.w;
    }
    v.x *= alpha; v.y *= alpha; v.z *= alpha; v.w *= alpha;
    ((float4*)C)[i] = v;
  }
}

// reduce + emit bf16 hi/lo planes (vectorized by 4)
__global__ __launch_bounds__(256) void k_reduce_split(float* __restrict__ C, const float* __restrict__ Part,
                                                      long total, int S, float alpha,
                                                      __bf16* __restrict__ H, __bf16* __restrict__ L){
  long n4 = total >> 2;
  for (long i = (long)blockIdx.x*blockDim.x + threadIdx.x; i < n4;
       i += (long)gridDim.x*blockDim.x){
    float4 v = ((float4*)C)[i];
    for (int s=0;s<S;++s){
      float4 p = ((const float4*)(Part + (long)s*total))[i];
      v.x += p.x; v.y += p.y; v.z += p.z; v.w += p.w;
    }
    v.x *= alpha; v.y *= alpha; v.z *= alpha; v.w *= alpha;
    ((float4*)C)[i] = v;
    float vv[4] = {v.x, v.y, v.z, v.w};
    bf16x4 h, l;
    #pragma unroll
    for (int e=0;e<4;++e){
      __bf16 hh = (__bf16)vv[e];
      h[e] = hh;
      l[e] = (__bf16)(vv[e] - (float)hh);
    }
    ((bf16x4*)H)[i] = h;
    ((bf16x4*)L)[i] = l;
  }
}

// flat fp32 -> bf16 hi/lo planes
__global__ __launch_bounds__(256) void k_split(const float* __restrict__ X,
                                               __bf16* __restrict__ H, __bf16* __restrict__ L, long n){
  long n4 = n >> 2;
  for (long i = (long)blockIdx.x*blockDim.x + threadIdx.x; i < n4;
       i += (long)gridDim.x*blockDim.x){
    float4 v = ((const float4*)X)[i];
    float vv[4] = {v.x, v.y, v.z, v.w};
    bf16x4 h, l;
    #pragma unroll
    for (int e=0;e<4;++e){
      __bf16 hh = (__bf16)vv[e];
      h[e] = hh;
      l[e] = (__bf16)(vv[e] - (float)hh);
    }
    ((bf16x4*)H)[i] = h;
    ((bf16x4*)L)[i] = l;
  }
}

// ---------------- fused skinny PV: bf16 planes + prefetch ----------------
__global__ __launch_bounds__(256, 2) void k_pv2(
    float* __restrict__ C, float* __restrict__ Part,
    const float* __restrict__ Pm, long sP, int K, int Kc,
    const __bf16* __restrict__ Gh, const __bf16* __restrict__ Gl,
    long sG, const int* __restrict__ SB)
{
  extern __shared__ float Pl[];   // [16][Kc]
  int b = blockIdx.y, ks = blockIdx.z;
  int kbeg = ks * Kc;
  int kend = min(K, kbeg + Kc);
  int len = kend - kbeg;
  int c0 = blockIdx.x*512 + threadIdx.x*2;
  const float* Pb = Pm + (long)b*sP;
  for (int i = threadIdx.x; i < 16*len; i += 256){
    int q = i / len, kk = i - q*len;
    Pl[q*Kc + kk] = Pb[(long)q*K + kbeg + kk];
  }
  __syncthreads();
  f32x2 acc[16];
  #pragma unroll
  for (int q=0;q<16;++q) acc[q] = (f32x2){0.f,0.f};
  int kk = 0;
  while (kk < len){
    int kg = kbeg + kk;
    int seg = kg / 288;
    int row = kg - seg*288;
    int nrow = min(288 - row, len - kk);
    long base = (SB ? (long)SB[(b<<2)+seg]*sG : (long)b*sG) + (long)row*2048 + c0;
    const __bf16* gh = Gh + base;
    const __bf16* gl = Gl + base;
    bf16x2 h0,h1,h2,h3,l0,l1,l2,l3;
    h0 = *(const bf16x2*)(gh);       l0 = *(const bf16x2*)(gl);
    h1 = *(const bf16x2*)(gh+2048);  l1 = *(const bf16x2*)(gl+2048);
    h2 = *(const bf16x2*)(gh+4096);  l2 = *(const bf16x2*)(gl+4096);
    h3 = *(const bf16x2*)(gh+6144);  l3 = *(const bf16x2*)(gl+6144);
    gh += 8192; gl += 8192;
    for (int r = 0; r < nrow; r += 4, kk += 4){
      bf16x2 nh0=h0,nh1=h1,nh2=h2,nh3=h3,nl0=l0,nl1=l1,nl2=l2,nl3=l3;
      if (r + 4 < nrow){
        nh0 = *(const bf16x2*)(gh);       nl0 = *(const bf16x2*)(gl);
        nh1 = *(const bf16x2*)(gh+2048);  nl1 = *(const bf16x2*)(gl+2048);
        nh2 = *(const bf16x2*)(gh+4096);  nl2 = *(const bf16x2*)(gl+4096);
        nh3 = *(const bf16x2*)(gh+6144);  nl3 = *(const bf16x2*)(gl+6144);
        gh += 8192; gl += 8192;
      }
      f32x2 g0, g1, g2, g3;
      g0[0]=(float)h0[0]+(float)l0[0]; g0[1]=(float)h0[1]+(float)l0[1];
      g1[0]=(float)h1[0]+(float)l1[0]; g1[1]=(float)h1[1]+(float)l1[1];
      g2[0]=(float)h2[0]+(float)l2[0]; g2[1]=(float)h2[1]+(float)l2[1];
      g3[0]=(float)h3[0]+(float)l3[0]; g3[1]=(float)h3[1]+(float)l3[1];
      #pragma unroll
      for (int q=0;q<16;++q){
        f32x4 p = *(const f32x4*)&Pl[q*Kc + kk];
        acc[q] += p[0]*g0;
        acc[q] += p[1]*g1;
        acc[q] += p[2]*g2;
        acc[q] += p[3]*g3;
      }
      h0=nh0; h1=nh1; h2=nh2; h3=nh3;
      l0=nl0; l1=nl1; l2=nl2; l3=nl3;
    }
  }
  float* Cw = (ks==0) ? C : (Part + (long)(ks-1)*1048576);
  long obase = (long)b*32768 + c0;
  #pragma unroll
  for (int q=0;q<16;++q) *(f32x2*)&Cw[obase + (long)q*2048] = acc[q];
}

// ---------------- small kernels ----------------
// transpose x -> XS planes + per-patch sum-of-squares (atomic)
__global__ void k_trs(const float* __restrict__ in, __bf16* __restrict__ oh,
                      __bf16* __restrict__ ol, float* __restrict__ m2){
  __shared__ float tile[32][33];
  __shared__ float cred[8][33];
  int bz = blockIdx.z;
  long zo = (long)bz*589824;
  int r0 = blockIdx.y*32, c0 = blockIdx.x*32;
  int tx = threadIdx.x, ty = threadIdx.y;
  float ss = 0.f;
  #pragma unroll
  for (int j=0;j<32;j+=8){
    float v = in[zo + (long)(r0+ty+j)*288 + c0+tx];
    tile[ty+j][tx] = v;
    ss += v*v;
  }
  cred[ty][tx] = ss;
  __syncthreads();
  #pragma unroll
  for (int j=0;j<32;j+=8){
    float v = tile[tx][ty+j];
    __bf16 h = (__bf16)v;
    long idx = zo + (long)(c0+ty+j)*2048 + r0+tx;
    oh[idx] = h;
    ol[idx] = (__bf16)(v - (float)h);
  }
  if (ty==0){
    float s = cred[0][tx];
    #pragma unroll
    for (int k=1;k<8;++k) s += cred[k][tx];
    atomicAdd(&m2[bz*288 + c0+tx], s);
  }
}

// transpose + split into bf16 hi/lo planes
__global__ void k_tr_split(const float* __restrict__ in, __bf16* __restrict__ oh,
                           __bf16* __restrict__ ol, int R, int C){
  __shared__ float tile[32][33];
  int r0 = blockIdx.y*32, c0 = blockIdx.x*32;
  int tx = threadIdx.x, ty = threadIdx.y;
  #pragma unroll
  for (int j=0;j<32;j+=8)
    tile[ty+j][tx] = in[(long)(r0+ty+j)*C + c0+tx];
  __syncthreads();
  #pragma unroll
  for (int j=0;j<32;j+=8){
    float v = tile[tx][ty+j];
    __bf16 h = (__bf16)v;
    long idx = (long)(c0+ty+j)*R + r0+tx;
    oh[idx] = h;
    ol[idx] = (__bf16)(v - (float)h);
  }
}

// batched rowstats: r<2048 -> X1 row, else X2 row (cols=2048)
__global__ __launch_bounds__(256) void k_rowstats2(const float* __restrict__ X1, const float* __restrict__ X2,
                                                   float* __restrict__ mu1, float* __restrict__ m21,
                                                   float* __restrict__ mu2, float* __restrict__ m22){
  int r = blockIdx.x;
  const float* row; float* mu; float* m2; int idx;
  if (r < 2048){ idx = r; row = X1 + (long)idx*2048; mu = mu1; m2 = m21; }
  else { idx = r - 2048; row = X2 + (long)idx*2048; mu = mu2; m2 = m22; }
  float s=0.f, s2=0.f;
  for (int c = threadIdx.x*4; c < 2048; c += 1024){
    float4 v = *(const float4*)(row+c);
    s  += v.x+v.y+v.z+v.w;
    s2 += v.x*v.x+v.y*v.y+v.z*v.z+v.w*v.w;
  }
  __shared__ float red[8];
  s  = block_sum(s,  red);
  s2 = block_sum(s2, red);
  if (threadIdx.x==0){ mu[idx]=s*(1.f/2048.f); m2[idx]=s2; }
}

// gram softmax: folded Part slice, l2norm scaling, emits S planes
__global__ __launch_bounds__(256) void k_softmax_gram_s(const float* __restrict__ S, const float* __restrict__ Part,
                                                        const float* __restrict__ m2xs,
                                                        __bf16* __restrict__ Hh, __bf16* __restrict__ Hl){
  int r = blockIdx.x;
  int b = r / 288, p = r % 288;
  const float* row = S + (long)r * 288;
  const float* prow = Part + (long)b*82944 + (long)p*288;
  const float* m2 = m2xs + (long)b*288;
  float rp = 1.f / fmaxf(sqrtf(m2[p]), 1e-12f);
  int tid = threadIdx.x;
  __shared__ float red[8];
  float lv[2];
  #pragma unroll
  for (int i=0;i<2;++i){
    int q = tid + i*256;
    lv[i] = (q<288) ? (row[q]+prow[q])*rp/fmaxf(sqrtf(m2[q]),1e-12f) : -1e30f;
  }
  float mx = fmaxf(lv[0], lv[1]);
  mx = block_max(mx, red);
  float s = 0.f;
  #pragma unroll
  for (int i=0;i<2;++i){
    int q = tid + i*256;
    float e = (q<288) ? expf(lv[i]-mx) : 0.f;
    lv[i]=e; s+=e;
  }
  s = block_sum(s, red);
  float inv = 1.f/s;
  #pragma unroll
  for (int i=0;i<2;++i){
    int q = tid + i*256;
    if (q<288){
      float v = lv[i]*inv;
      __bf16 h = (__bf16)v;
      long idx = (long)r*288 + q;
      Hh[idx] = h;
      Hl[idx] = (__bf16)(v - (float)h);
    }
  }
}

// softmax over rows of X[32*16][288] with folded Part sum
__global__ __launch_bounds__(256) void k_softmax_plain_r(float* __restrict__ X,
                                                         const float* __restrict__ Part,
                                                         int S, float alpha){
  int r = blockIdx.x; int b = r>>4, qq = r&15;
  float* row = X + (long)r * 288;
  int tid = threadIdx.x;
  __shared__ float red[8];
  float lv[2];
  #pragma unroll
  for (int i=0;i<2;++i){
    int q = tid + i*256;
    if (q<288){
      float v = row[q];
      for (int s=0;s<S;++s) v += Part[((long)s*32 + b)*4608 + (long)qq*288 + q];
      lv[i] = v*alpha;
    } else lv[i] = -1e30f;
  }
  float mx = fmaxf(lv[0], lv[1]);
  mx = block_max(mx, red);
  float s = 0.f;
  #pragma unroll
  for (int i=0;i<2;++i){ int q = tid + i*256; float e = (q<288)?expf(lv[i]-mx):0.f; lv[i]=e; s+=e; }
  s = block_sum(s, red);
  float inv = 1.f/s;
  #pragma unroll
  for (int i=0;i<2;++i){ int q = tid + i*256; if (q<288) row[q]=lv[i]*inv; }
}

// segmented softmax with folded SCOR Part (Ss slices) and CC Part (Sc slices)
__global__ __launch_bounds__(256) void k_softmax_seg(float* __restrict__ X, const float* __restrict__ PartS,
                                                     int Ss,
                                                     const float* __restrict__ CC,
                                                     const float* __restrict__ PartC, int Sc,
                                                     const int* __restrict__ SB, float scale){
  int r = blockIdx.x; int b = r>>4, qq = r&15;
  float* row = X + (long)r*1152;
  float bias[4];
  #pragma unroll
  for (int j=0;j<4;++j){
    int col = SB[b*4+j];
    float cv = CC[(long)r*32 + col];
    for (int s=0;s<Sc;++s) cv += PartC[(long)s*16384 + (long)r*32 + col];
    bias[j] = scale*cv;
  }
  int tid = threadIdx.x;
  __shared__ float red[8];
  float lv[5];
  #pragma unroll
  for (int i=0;i<5;++i){
    int q = tid + i*256;
    if (q<1152){
      float v = row[q];
      for (int s=0;s<Ss;++s) v += PartS[((long)s*32 + b)*18432 + (long)qq*1152 + q];
      lv[i] = v*scale + bias[q/288];
    } else lv[i] = -1e30f;
  }
  float mx = -1e30f;
  #pragma unroll
  for (int i=0;i<5;++i) mx = fmaxf(mx, lv[i]);
  mx = block_max(mx, red);
  float s = 0.f;
  #pragma unroll
  for (int i=0;i<5;++i){ int q = tid + i*256; float e = (q<1152)?expf(lv[i]-mx):0.f; lv[i]=e; s+=e; }
  s = block_sum(s, red);
  float inv = 1.f/s;
  #pragma unroll
  for (int i=0;i<5;++i){ int q = tid + i*256; if (q<1152) row[q]=lv[i]*inv; }
}

// F_REL finalize: sum PV parts, write final F_REL, row LN -> QLN planes
__global__ __launch_bounds__(256) void k_finalize_frel(float* __restrict__ F, const float* __restrict__ Part,
                                                       int S, __bf16* __restrict__ H, __bf16* __restrict__ L){
  int r = blockIdx.x;
  long ro = (long)r*2048;
  int tid = threadIdx.x;
  float4 vbuf[2];
  float s=0.f, s2=0.f;
  #pragma unroll
  for (int i=0;i<2;++i){
    long c = (long)tid*4 + i*1024;
    float4 a = *(const float4*)&F[ro+c];
    for (int ss=0; ss<S; ++ss){
      float4 p = *(const float4*)&Part[(long)ss*1048576 + ro + c];
      a.x += p.x; a.y += p.y; a.z += p.z; a.w += p.w;
    }
    vbuf[i] = a;
    *(float4*)&F[ro+c] = a;
    s  += a.x+a.y+a.z+a.w;
    s2 += a.x*a.x+a.y*a.y+a.z*a.z+a.w*a.w;
  }
  __shared__ float red[8];
  s  = block_sum(s,  red);
  s2 = block_sum(s2, red);
  float m = s*(1.f/2048.f);
  float var = s2*(1.f/2048.f) - m*m;
  float inv = rsqrtf(var + 1e-5f);
  #pragma unroll
  for (int i=0;i<2;++i){
    long c = (long)tid*4 + i*1024;
    float vv[4] = {vbuf[i].x, vbuf[i].y, vbuf[i].z, vbuf[i].w};
    bf16x4 h, l;
    #pragma unroll
    for (int e=0;e<4;++e){
      float y = (vv[e]-m)*inv;
      __bf16 hh = (__bf16)y;
      h[e] = hh;
      l[e] = (__bf16)(y - (float)hh);
    }
    *(bf16x4*)&H[ro+c] = h;
    *(bf16x4*)&L[ro+c] = l;
  }
}

// meanx + its rowstats fused: per-b block
__global__ __launch_bounds__(256) void k_meanx_stats(const float* __restrict__ frel, float* __restrict__ mx,
                                                     float* __restrict__ mu_m, float* __restrict__ m2_m){
  int b = blockIdx.x;
  const float* base = frel + (long)b*32768;
  int tid = threadIdx.x;
  float s=0.f, s2=0.f;
  #pragma unroll
  for (int i=0;i<2;++i){
    long c = (long)tid*4 + i*1024;
    float4 a = make_float4(0.f,0.f,0.f,0.f);
    #pragma unroll
    for (int q=0;q<16;++q){
      float4 v = *(const float4*)&base[(long)q*2048 + c];
      a.x += v.x; a.y += v.y; a.z += v.z; a.w += v.w;
    }
    a.x *= (1.f/16.f); a.y *= (1.f/16.f); a.z *= (1.f/16.f); a.w *= (1.f/16.f);
    *(float4*)&mx[(long)b*2048 + c] = a;
    s  += a.x+a.y+a.z+a.w;
    s2 += a.x*a.x+a.y*a.y+a.z*a.z+a.w*a.w;
  }
  __shared__ float red[8];
  s  = block_sum(s,  red);
  s2 = block_sum(s2, red);
  if (tid==0){ mu_m[b]=s*(1.f/2048.f); m2_m[b]=s2; }
}

// sigma with folded PM part slices
__global__ void k_sigma_r(const float* __restrict__ pm, const float* __restrict__ PartPM, int Sp,
                          const float* __restrict__ mu_p, const float* __restrict__ m2_p,
                          const float* __restrict__ mu_m, const float* __restrict__ m2_m,
                          float* __restrict__ sigma){
  int b = blockIdx.y; int n = blockIdx.x*256 + threadIdx.x;
  float pmv = pm[(long)b*2048+n];
  for (int s=0;s<Sp;++s) pmv += PartPM[(long)s*65536 + (long)b*2048 + n];
  float mp = mu_p[n], mm = mu_m[b];
  float vp = m2_p[n]*(1.f/2048.f) - mp*mp;
  float vm = m2_m[b]*(1.f/2048.f) - mm*mm;
  float cov = pmv*(1.f/2048.f) - mp*mm;
  sigma[(long)b*2048+n] = sqrtf(fmaxf(vp + vm - 2.f*cov, 0.f) + 1e-5f);
}

// fused: qm/qw dots (with folded MX parts + rank-1 fixrow algebra) + score softmax + QPW planes
__global__ __launch_bounds__(256) void k_score2f(const float* __restrict__ QP, const float* __restrict__ QPpart, int Sq,
                                                 const float* __restrict__ relq2,
                                                 const float* __restrict__ MX, const float* __restrict__ MXpart, int Sm,
                                                 const float* __restrict__ muw, const float* __restrict__ mu_m,
                                                 const float* __restrict__ sigma, const float* __restrict__ mu_p,
                                                 __bf16* __restrict__ QH, __bf16* __restrict__ QL,
                                                 float* __restrict__ W1, float* __restrict__ Wmu, float scale){
  int r = blockIdx.x; int b = r >> 4;
  int tid = threadIdx.x;
  __shared__ float red[8];
  // pass 1: qm = dot(relq2[r], MX_sum[b]); qw = dot(relq2[r], mu_w)
  float qm=0.f, qw=0.f;
  for (int c = tid*4; c < 2048; c += 1024){
    float4 va = *(const float4*)&relq2[(long)r*2048 + c];
    float4 vm = *(const float4*)&MX[(long)b*2048 + c];
    for (int s=0;s<Sm;++s){
      float4 p = *(const float4*)&MXpart[(long)s*65536 + (long)b*2048 + c];
      vm.x += p.x; vm.y += p.y; vm.z += p.z; vm.w += p.w;
    }
    float4 vw = *(const float4*)&muw[c];
    qm += va.x*vm.x+va.y*vm.y+va.z*vm.z+va.w*vm.w;
    qw += va.x*vw.x+va.y*vw.y+va.z*vw.z+va.w*vw.w;
  }
  qm = block_sum(qm, red);
  qw = block_sum(qw, red);
  float qmr = qm - 2048.f*mu_m[b]*qw;   // folds the deleted fixrow(MX)
  float qwr2048 = 2048.f*qw;
  const float* sg = sigma + (long)b*2048;
  float lv[8], ls[8], lmp[8];
  #pragma unroll
  for (int i=0;i<8;++i){
    int n = tid + i*256;
    float qpv = QP[(long)r*2048 + n];
    for (int s=0;s<Sq;++s) qpv += QPpart[(long)s*1048576 + (long)r*2048 + n];
    float sgn = sg[n];
    float mpn = mu_p[n];
    ls[i] = sgn;
    lmp[i] = mpn;
    lv[i] = scale * (qpv - qwr2048*mpn - qmr) / sgn;
  }
  float mx = -1e30f;
  #pragma unroll
  for (int i=0;i<8;++i) mx = fmaxf(mx, lv[i]);
  mx = block_max(mx, red);
  float se=0.f, sw=0.f, swm=0.f;
  #pragma unroll
  for (int i=0;i<8;++i){
    float e = expf(lv[i]-mx);
    lv[i] = e; se += e;
    float wv = e/ls[i];
    sw += wv; swm += wv*lmp[i];
  }
  se  = block_sum(se,  red);
  sw  = block_sum(sw,  red);
  swm = block_sum(swm, red);
  float inv = 1.f/se;
  #pragma unroll
  for (int i=0;i<8;++i){
    int n = tid + i*256;
    float v = lv[i]*inv/ls[i];
    __bf16 h = (__bf16)v;
    long idx = (long)r*2048 + n;
    QH[idx] = h;
    QL[idx] = (__bf16)(v - (float)h);
  }
  if (tid==0){ W1[r]=sw*inv; Wmu[r]=swm*inv; }
}

// fpro final: emits FPRO bf16 planes + fp32 weighted output
__global__ void k_fpro_final_s(const float* __restrict__ frel, const float* __restrict__ out2,
                               const float* __restrict__ meanx, const float* __restrict__ mu_m,
                               const float* __restrict__ W1, const float* __restrict__ Wmu,
                               const float* __restrict__ wsm,
                               __bf16* __restrict__ FH, __bf16* __restrict__ FL,
                               float* __restrict__ fout){
  int r = blockIdx.y; int c = blockIdx.x*256 + threadIdx.x;
  int b = r >> 4, q = r & 15;
  long idx = (long)r*2048 + c;
  float w1 = W1[r];
  float v = frel[idx] + out2[idx] - meanx[(long)b*2048+c]*w1 - Wmu[r] + mu_m[b]*w1;
  __bf16 h = (__bf16)v;
  FH[idx] = h;
  FL[idx] = (__bf16)(v - (float)h);
  fout[idx] = wsm[q] * v;
}

// cam embed gather -> bf16 hi/lo planes
__global__ void k_camb(const float* __restrict__ cam_table, const int* __restrict__ cam_ids,
                       __bf16* __restrict__ H, __bf16* __restrict__ L){
  int b = blockIdx.y; int c = blockIdx.x*256 + threadIdx.x;
  float v = cam_table[(long)(cam_ids[b]-1)*2048 + c];
  __bf16 h = (__bf16)v;
  long idx = (long)b*2048 + c;
  H[idx] = h;
  L[idx] = (__bf16)(v - (float)h);
}

// perm + gidx + SB + weight softmax (merged tiny kernels)
__global__ void k_permw(const void* __restrict__ subp, const float* __restrict__ w,
                        int* __restrict__ gidx, int* __restrict__ SB, float* __restrict__ wsm){
  __shared__ int perm[32];
  if (threadIdx.x==0){
    const int* pi = (const int*)subp;
    const float* pf = (const float*)subp;
    const unsigned char* pb = (const unsigned char*)subp;
    int sv[32]; bool okI=true, okF=true;
    for (int i=0;i<32;++i){ int v=pi[i]; if (v!=0 && v!=1) okI=false; }
    for (int i=0;i<32;++i){ float f=pf[i]; if (f!=0.f && f!=1.f) okF=false; }
    for (int i=0;i<32;++i){
      if (okI) sv[i]=pi[i];
      else if (okF) sv[i]=(pf[i]!=0.f)?1:0;
      else sv[i]=(pb[i]!=0)?1:0;
    }
    int pos=0;
    for (int i=0;i<32;++i) if (!sv[i]) perm[pos++]=i;
    for (int i=0;i<32;++i) if ( sv[i]) perm[pos++]=i;
    // weight softmax
    float mx=-1e30f;
    for (int i=0;i<16;++i) mx=fmaxf(mx,w[i]);
    float e[16], s=0.f;
    for (int i=0;i<16;++i){ e[i]=expf(w[i]-mx); s+=e[i]; }
    for (int i=0;i<16;++i) wsm[i]=e[i]/s;
  }
  __syncthreads();
  for (int i = threadIdx.x; i < 128; i += blockDim.x){
    int b = i>>2, j = i&3;
    SB[i] = ((perm[b]>>2)<<2) + j;
  }
  for (int idx = threadIdx.x; idx < 32*1152; idx += blockDim.x){
    int b = idx / 1152, rem = idx % 1152, j = rem / 288, n = rem % 288;
    int src = ((perm[b] >> 2) << 2) + j;
    gidx[idx] = src*288 + n;
  }
}

// ---------------- launcher ----------------
extern "C" void kernel_launch(void* const* d_in, const int* in_sizes, int n_in,
                              void* d_out, int out_size, void* d_ws, size_t ws_size,
                              hipStream_t stream) {
  const float* x        = (const float*)d_in[0];   // [32,2048,288]
  const int*   cam_ids  = (const int*)d_in[1];
  const void*  subp     = d_in[2];
  const float* query_v  = (const float*)d_in[3];   // [16,2048]
  const float* proto    = (const float*)d_in[4];   // [2048,2048]
  const float* weights  = (const float*)d_in[5];   // [16]
  const float* cam_tab  = (const float*)d_in[6];   // [6,2048]
  const float* Wcq      = (const float*)d_in[8];
  const float* Wcg      = (const float*)d_in[9];
  const float* Wdq      = (const float*)d_in[10];
  const float* Wdg      = (const float*)d_in[11];
  float* out = (float*)d_out;
  float* ws  = (float*)d_ws;

  size_t o = 0;
  float* S     = ws + o; o += 2654208;   // S fp32 (gram out); later hosts QLN/RELQ2 planes
  __bf16* QLNh   = (__bf16*)S;
  __bf16* QLNl   = (__bf16*)(S + 524288);
  __bf16* RELQ2h = (__bf16*)(S + 1048576);
  __bf16* RELQ2l = (__bf16*)(S + 1572864);
  float* XSR   = ws + o; o += 18874368;  // XS planes; then S planes + PART + weight planes
  __bf16* XSh = (__bf16*)XSR;
  __bf16* XSl = XSh + 18874368;
  __bf16* Shp = (__bf16*)XSR;            // S planes (after gram consumed XS planes)
  __bf16* Slp = Shp + 2654208;
  float* PART  = XSR;                    // [0, 6.29M) floats
  __bf16* WCQh  = (__bf16*)(XSR + 6291456);
  __bf16* WCQl  = (__bf16*)(XSR + 8388608);
  __bf16* WCGTh = (__bf16*)(XSR + 10485760);
  __bf16* WCGTl = (__bf16*)(XSR + 12582912);
  __bf16* ROTh  = (__bf16*)(XSR + 14680064);
  __bf16* ROTl  = (__bf16*)(XSR + 16777216);
  float* GMIXR = ws + o; o += 18874368;  // gram Part, then GMIX planes
  __bf16* GMIXh = (__bf16*)GMIXR;
  __bf16* GMIXl = GMIXh + 18874368;
  float* M2_XS = ws + o; o += 9216;
  float* CAMB  = ws + o; o += 65536;
  __bf16* CAMBh = (__bf16*)CAMB;
  __bf16* CAMBl = CAMBh + 65536;
  float* RQ0   = ws + o; o += 32768;
  float* RQW   = ws + o; o += 32768;
  float* SREL  = ws + o; o += 147456;
  float* T1    = ws + o; o += 1048576;
  float* RELQ2 = ws + o; o += 1048576;
  float* MEANX = ws + o; o += 65536;
  float* MU_P  = ws + o; o += 2048;
  float* M2_P  = ws + o; o += 2048;
  float* MU_M  = ws + o; o += 64;
  float* M2_M  = ws + o; o += 64;
  float* MU_W  = ws + o; o += 2048;
  float* M2_W  = ws + o; o += 2048;
  float* PM    = ws + o; o += 65536;
  float* SIGMA = ws + o; o += 65536;
  float* MX    = ws + o; o += 65536;
  float* QP    = ws + o; o += 1048576;
  float* W1    = ws + o; o += 512;
  float* WMU   = ws + o; o += 512;
  float* OUT2  = ws + o; o += 1048576;
  __bf16* FPROh = (__bf16*)(ws + o);
  __bf16* FPROl = (__bf16*)(ws + o + 524288); o += 1048576;
  float* RQ2   = ws + o; o += 1048576;
  float* RQW2  = ws + o; o += 1048576;
  __bf16* RQW2h = (__bf16*)(ws + o);
  __bf16* RQW2l = RQW2h + 1048576; o += 1048576;
  float* SREC  = ws + o; o += 147456;
  float* SCOR  = ws + o; o += 589824;
  float* CC    = ws + o; o += 16384;
  float* WSM   = ws + o; o += 16;
  __bf16* T1h   = (__bf16*)(ws + o);
  __bf16* T1l   = (__bf16*)(ws + o + 524288); o += 1048576;
  __bf16* QPWh  = (__bf16*)(ws + o);
  __bf16* QPWl  = (__bf16*)(ws + o + 524288); o += 1048576;
  __bf16* RQ2h  = (__bf16*)(ws + o);
  __bf16* RQ2l  = (__bf16*)(ws + o + 524288); o += 1048576;
  __bf16* QVh   = (__bf16*)(ws + o);
  __bf16* QVl   = (__bf16*)(ws + o + 16384); o += 32768;
  __bf16* RQ0h  = (__bf16*)(ws + o);
  __bf16* RQ0l  = (__bf16*)(ws + o + 16384); o += 32768;
  __bf16* RQWh  = (__bf16*)(ws + o);
  __bf16* RQWl  = RQWh + 32768; o += 32768;
  int*   GIDX  = (int*)(ws + o); o += 36864;
  int*   SB    = (int*)(ws + o); o += 128;

  float* F_REL = out;
  float* F_PRO = out + 1048576;
  float* F_REC = out + 2097152;
  float* F_COR = out + 3145728;

  float* PART_CC = PART + 4000000;   // CC slices (7 x 16384)
  float* PART_MX = PART + 3145728;   // MX slices (7 x 65536), survives QP's [0,2M)

  // ---- Phase A ----
  hipMemsetAsync(M2_XS, 0, 9216*sizeof(float), stream);
  k_trs<<<dim3(9,64,32), dim3(32,8), 0, stream>>>(x, XSh, XSl, M2_XS);
  gemm_nt_bsg<3,3,2,2><<<576, 256, 0, stream>>>(S, XSh,XSl, XSh,XSl,
      288,288,2048, 2048,2048,288, 589824,589824,82944, 1.f, nullptr,0, 3,3,64, 2, GMIXR);
  k_softmax_gram_s<<<9216, 256, 0, stream>>>(S, GMIXR, M2_XS, Shp, Slp);
  gemm_gmix<<<1536, 256, 0, stream>>>(Shp, Slp, x, GMIXh, GMIXl);
  k_split<<<2048, 256, 0, stream>>>(Wcq, WCQh, WCQl, 4194304L);
  k_tr_split<<<dim3(64,64), dim3(32,8), 0, stream>>>(Wcg, WCGTh, WCGTl, 2048, 2048);
  k_split<<<32, 256, 0, stream>>>(query_v, QVh, QVl, 32768L);
  k_camb<<<dim3(8,32), 256, 0, stream>>>(cam_tab, cam_ids, CAMBh, CAMBl);
  k_permw<<<1, 256, 0, stream>>>(subp, weights, GIDX, SB, WSM);

  // ---- f_rel ----
  gemm_nt_bsg<1,4,1,4><<<128, 256, 0, stream>>>(RQ0, QVh,QVl, WCQh,WCQl,
      16,2048,2048, 2048,2048,2048, 0,0,0, 1.f, nullptr,0, 8,1,16, 16, PART);
  k_reduce_split<<<64, 256, 0, stream>>>(RQ0, PART, 32768L, 15, 1.f, RQ0h, RQ0l);
  gemm_nt_bsg<1,4,1,4><<<128, 256, 0, stream>>>(RQW, RQ0h,RQ0l, WCGTh,WCGTl,
      16,2048,2048, 2048,2048,2048, 0,0,0, 1.f, nullptr,0, 8,1,16, 16, PART);
  k_reduce_split<<<64, 256, 0, stream>>>(RQW, PART, 32768L, 15, 1.f, RQWh, RQWl);
  gemm_nt_bsg<1,4,1,4><<<512, 256, 0, stream>>>(SREL, RQWh,RQWl, GMIXh,GMIXl,
      16,288,2048, 2048,2048,288, 0,589824,4608, SCALE, nullptr,0, 2,1,256, 8, PART);
  k_softmax_plain_r<<<512, 256, 0, stream>>>(SREL, PART, 7, SCALE);
  k_pv2<<<dim3(4,32,7), 256, 16*44*4, stream>>>(F_REL, PART, SREL, 4608, 288, 44,
      GMIXh, GMIXl, 589824, nullptr);
  k_finalize_frel<<<512, 256, 0, stream>>>(F_REL, PART, 6, QLNh, QLNl);

  // ---- deltaor ----
  k_meanx_stats<<<32, 256, 0, stream>>>(F_REL, MEANX, MU_M, M2_M);
  k_rowstats2<<<4096, 256, 0, stream>>>(proto, Wdg, MU_P, M2_P, MU_W, M2_W);
  k_split<<<2048, 256, 0, stream>>>(Wdq, ROTh, ROTl, 4194304L);
  gemm_nt_bsg<2,2,2,2><<<768, 256, 0, stream>>>(RELQ2, QLNh,QLNl, ROTh,ROTl,
      512,2048,2048, 2048,2048,2048, 0,0,0, 1.f, nullptr,0, 32,8,3, 3, PART);
  k_reduce_split<<<1024, 256, 0, stream>>>(RELQ2, PART, 1048576L, 2, 1.f, RELQ2h, RELQ2l);
  gemm_nt_mfma<1,4,1,4><<<dim3(8,2,8), 256, 0, stream>>>(PM, MEANX, proto, 32,2048,2048,
      2048,2048,2048, 0,0,0, 1.f, 8, PART);
  k_sigma_r<<<dim3(8,32), 256, 0, stream>>>(PM, PART, 7, MU_P, M2_P, MU_M, M2_M, SIGMA);
  k_tr_split<<<dim3(64,64), dim3(32,8), 0, stream>>>(Wdg, ROTh, ROTl, 2048, 2048);  // WDGT
  gemm_nt_bsg<2,2,2,2><<<768, 256, 0, stream>>>(T1, RELQ2h,RELQ2l, ROTh,ROTl,
      512,2048,2048, 2048,2048,2048, 0,0,0, 1.f, nullptr,0, 32,8,3, 3, PART);
  k_reduce_split<<<1024, 256, 0, stream>>>(T1, PART, 1048576L, 2, 1.f, T1h, T1l);
  gemm_nt_mfma<1,4,1,4><<<dim3(8,2,8), 256, 0, stream>>>(MX, MEANX, Wdg, 32,2048,2048,
      2048,2048,2048, 0,0,0, 1.f, 8, PART_MX);
  k_split<<<2048, 256, 0, stream>>>(proto, ROTh, ROTl, 4194304L);
  gemm_nt_bsg<2,2,2,2><<<768, 256, 0, stream>>>(QP, T1h,T1l, ROTh,ROTl,
      512,2048,2048, 2048,2048,2048, 0,0,0, 1.f, nullptr,0, 32,8,3, 3, PART);
  k_score2f<<<512, 256, 0, stream>>>(QP, PART, 2, RELQ2, MX, PART_MX, 7,
      MU_W, MU_M, SIGMA, MU_P, QPWh, QPWl, W1, WMU, SCALE);
  k_tr_split<<<dim3(64,64), dim3(32,8), 0, stream>>>(proto, ROTh, ROTl, 2048, 2048); // PROTOT
  gemm_nt_bsg<2,2,2,2><<<768, 256, 0, stream>>>(OUT2, QPWh,QPWl, ROTh,ROTl,
      512,2048,2048, 2048,2048,2048, 0,0,0, 1.f, nullptr,0, 32,8,3, 3, PART);
  k_reduce4<<<1024, 256, 0, stream>>>(OUT2, PART, 1048576L, 2, 1.f);
  k_fpro_final_s<<<dim3(8,512), 256, 0, stream>>>(F_REL, OUT2, MEANX, MU_M, W1, WMU, WSM,
                                                  FPROh, FPROl, F_PRO);

  // ---- f_rec ----
  gemm_nt_bsg<2,2,2,2><<<768, 256, 0, stream>>>(RQ2, FPROh,FPROl, WCQh,WCQl,
      512,2048,2048, 2048,2048,2048, 0,0,0, 1.f, nullptr,0, 32,8,3, 3, PART);
  k_reduce_split<<<1024, 256, 0, stream>>>(RQ2, PART, 1048576L, 2, 1.f, RQ2h, RQ2l);
  gemm_nt_bsg<2,2,2,2><<<768, 256, 0, stream>>>(RQW2, RQ2h,RQ2l, WCGTh,WCGTl,
      512,2048,2048, 2048,2048,2048, 0,0,0, 1.f, nullptr,0, 32,8,3, 3, PART);
  k_reduce_split<<<1024, 256, 0, stream>>>(RQW2, PART, 1048576L, 2, 1.f, RQW2h, RQW2l);
  gemm_nt_bsg<1,4,1,4><<<512, 256, 0, stream>>>(SREC, RQW2h,RQW2l, GMIXh,GMIXl,
      16,288,2048, 2048,2048,288, 32768,589824,4608, SCALE, nullptr,0, 2,1,256, 8, PART);
  k_softmax_plain_r<<<512, 256, 0, stream>>>(SREC, PART, 7, SCALE);
  k_pv2<<<dim3(4,32,7), 256, 16*44*4, stream>>>(F_REC, PART, SREC, 4608, 288, 44,
      GMIXh, GMIXl, 589824, nullptr);
  k_reduce4<<<1024, 256, 0, stream>>>(F_REC, PART, 1048576L, 6, 1.f);

  // ---- f_cor ----
  gemm_nt_bsg<1,4,1,4><<<256, 256, 0, stream>>>(CC, RQW2h,RQW2l, CAMBh,CAMBl,
      512,32,2048, 2048,2048,32, 0,0,0, 1.f, nullptr,0, 1,32,8, 8, PART_CC);
  gemm_nt_bsg<1,4,1,4><<<640, 256, 0, stream>>>(SCOR, RQW2h,RQW2l, GMIXh,GMIXl,
      16,1152,2048, 2048,2048,1152, 32768,0,18432, SCALE, GIDX,1152, 5,1,128, 4, PART);
  k_softmax_seg<<<512, 256, 0, stream>>>(SCOR, PART, 3, CC, PART_CC, 7, SB, SCALE);
  k_pv2<<<dim3(4,32,7), 256, 16*168*4, stream>>>(F_COR, PART, SCOR, 18432, 1152, 168,
      GMIXh, GMIXl, 589824, SB);
  k_reduce4<<<1024, 256, 0, stream>>>(F_COR, PART, 1048576L, 6, 1.f);
}